// Round 1
// baseline (1282.775 us; speedup 1.0000x reference)
//
#include <hip/hip_runtime.h>

#define HSZ 128
#define NEGRID 100

// ---------- float <-> order-preserving uint (for atomic float max) ----------
__device__ __forceinline__ unsigned encf(float f) {
  unsigned i = __float_as_uint(f);
  return (i & 0x80000000u) ? ~i : (i | 0x80000000u);
}
__device__ __forceinline__ float decf(unsigned u) {
  return (u & 0x80000000u) ? __uint_as_float(u & 0x7fffffffu) : __uint_as_float(~u);
}

// ---------- h = x@node_w + node_b ; e = edge_attr@edgep_w + edgep_b ----------
__global__ void k_embed(const float* __restrict__ x, const float* __restrict__ ea,
                        const float* __restrict__ nw, const float* __restrict__ nb,
                        const float* __restrict__ ew, const float* __restrict__ eb,
                        float* __restrict__ h, float* __restrict__ e,
                        float* __restrict__ smean, int N, int E) {
  int row = blockIdx.x, c = threadIdx.x;
  if (row == 0 && c < 16) smean[c] = 0.f;
  if (row < N) {
    float acc = nb[c];
#pragma unroll
    for (int k = 0; k < 4; ++k) acc += x[row * 4 + k] * nw[k * 128 + c];
    h[row * 128 + c] = acc;
  } else {
    int ei = row - N;
    float acc = eb[c];
#pragma unroll
    for (int k = 0; k < 5; ++k) acc += ea[ei * 5 + k] * ew[k * 128 + c];
    e[ei * 128 + c] = acc;
  }
}

// ---------- per layer: xl = h@W (nodes), s_src/s_dst per node; s_edge per edge ----------
__global__ void k_gat_lin(const float* __restrict__ h, const float* __restrict__ e,
                          const float* __restrict__ W, const float* __restrict__ We,
                          const float* __restrict__ asrc, const float* __restrict__ adst,
                          const float* __restrict__ aedge,
                          float* __restrict__ xl, float* __restrict__ ssrc,
                          float* __restrict__ sdst, float* __restrict__ sedge,
                          float* __restrict__ smean4, unsigned* __restrict__ menc,
                          float* __restrict__ den, float* __restrict__ outacc,
                          int N, int E) {
  __shared__ float row_lds[128];
  __shared__ float red[128];
  __shared__ float red2[128];
  int row = blockIdx.x, c = threadIdx.x;
  const float* M;
  if (row < N) { row_lds[c] = h[row * 128 + c]; M = W; }
  else         { row_lds[c] = e[(row - N) * 128 + c]; M = We; }
  __syncthreads();
  float acc = 0.f;
  for (int k = 0; k < 128; ++k) acc += row_lds[k] * M[k * 128 + c];
  if (row < N) {
    xl[row * 128 + c] = acc;
    outacc[row * 128 + c] = 0.f;
    if (c < 4) { menc[row * 4 + c] = 0u; den[row * 4 + c] = 0.f; }
    red[c]  = acc * asrc[c];
    red2[c] = acc * adst[c];
    __syncthreads();
    if (c < 8) {
      int hh = c & 3;
      const float* b = (c < 4) ? red : red2;
      float s = 0.f;
      for (int t = 0; t < 32; ++t) s += b[hh * 32 + t];
      if (c < 4) ssrc[row * 4 + hh] = s; else sdst[row * 4 + hh] = s;
    }
  } else {
    int ei = row - N;
    red[c] = acc * aedge[c];
    __syncthreads();
    if (c < 4) {
      float s = 0.f;
      for (int t = 0; t < 32; ++t) s += red[c * 32 + t];
      sedge[ei * 4 + c] = s;
      atomicAdd(&smean4[c], s);
    }
  }
}

// ---------- alpha (leaky-relu) + atomic segment max over dst ----------
__global__ void k_alpha(const float* __restrict__ ssrc, const float* __restrict__ sdst,
                        const float* __restrict__ sedge, const float* __restrict__ smean4,
                        const int* __restrict__ srcI, const int* __restrict__ dstI,
                        float* __restrict__ alpha, unsigned* __restrict__ menc,
                        int N, int E, float invE) {
  int gid = blockIdx.x * 256 + threadIdx.x;
  if (gid >= (E + N) * 4) return;
  int item = gid >> 2, hh = gid & 3;
  float a; int dnode;
  if (item < E) {
    a = ssrc[srcI[item] * 4 + hh] + sdst[dstI[item] * 4 + hh] + sedge[item * 4 + hh];
    dnode = dstI[item];
  } else {
    int n = item - E;
    a = ssrc[n * 4 + hh] + sdst[n * 4 + hh] + smean4[hh] * invE;
    dnode = n;
  }
  a = (a > 0.f) ? a : 0.2f * a;
  alpha[gid] = a;
  atomicMax(&menc[dnode * 4 + hh], encf(a));
}

// ---------- exp + atomic den / weighted-feature scatter ----------
__global__ void k_scatter(const float* __restrict__ alpha, const unsigned* __restrict__ menc,
                          const float* __restrict__ xl, const int* __restrict__ srcI,
                          const int* __restrict__ dstI, float* __restrict__ den,
                          float* __restrict__ outacc, int N, int E) {
  int item = blockIdx.x, c = threadIdx.x, hh = c >> 5;
  int sn, dn;
  if (item < E) { sn = srcI[item]; dn = dstI[item]; } else { sn = dn = item - E; }
  float m = decf(menc[dn * 4 + hh]);
  float ex = expf(alpha[item * 4 + hh] - m);
  atomicAdd(&outacc[dn * 128 + c], xl[sn * 128 + c] * ex);
  if (c < 4) {
    float ex2 = expf(alpha[item * 4 + c] - decf(menc[dn * 4 + c]));
    atomicAdd(&den[dn * 4 + c], ex2);
  }
}

// ---------- hc = out/den + bias; h = LN(relu(hc)+h) ----------
__global__ void k_norm(const float* __restrict__ outacc, const float* __restrict__ den,
                       const float* __restrict__ bias, const float* __restrict__ lns,
                       const float* __restrict__ lnb, float* __restrict__ h, int N) {
  __shared__ float buf[128];
  int n = blockIdx.x, c = threadIdx.x, hh = c >> 5;
  float v = outacc[n * 128 + c] / den[n * 4 + hh] + bias[c];
  v = fmaxf(v, 0.f) + h[n * 128 + c];
  buf[c] = v;
  __syncthreads();
  for (int s = 64; s > 0; s >>= 1) { if (c < s) buf[c] += buf[c + s]; __syncthreads(); }
  float mean = buf[0] * (1.f / 128.f);
  __syncthreads();
  float dv = v - mean;
  buf[c] = dv * dv;
  __syncthreads();
  for (int s = 64; s > 0; s >>= 1) { if (c < s) buf[c] += buf[c + s]; __syncthreads(); }
  float var = buf[0] * (1.f / 128.f);
  h[n * 128 + c] = dv * (1.0f / sqrtf(var + 1e-5f)) * lns[c] + lnb[c];
}

// ---------- onsite / coupling MLPs (128 -> 64 -> 1) ----------
__global__ void k_mlp(const float* __restrict__ h, const float* __restrict__ e,
                      const float* __restrict__ w1n, const float* __restrict__ b1n,
                      const float* __restrict__ w2n, const float* __restrict__ b2n,
                      const float* __restrict__ w1e, const float* __restrict__ b1e,
                      const float* __restrict__ w2e, const float* __restrict__ b2e,
                      float* __restrict__ onsite, float* __restrict__ coup, int N, int E) {
  int row = blockIdx.x, t = threadIdx.x;
  const float *vec, *w1, *b1, *w2; float b2v;
  if (row < N) { vec = h + (size_t)row * 128; w1 = w1n; b1 = b1n; w2 = w2n; b2v = b2n[0]; }
  else         { vec = e + (size_t)(row - N) * 128; w1 = w1e; b1 = b1e; w2 = w2e; b2v = b2e[0]; }
  float acc = b1[t];
  for (int k = 0; k < 128; ++k) acc += vec[k] * w1[k * 64 + t];
  acc = fmaxf(acc, 0.f) * w2[t];
#pragma unroll
  for (int off = 32; off; off >>= 1) acc += __shfl_down(acc, off);
  if (t == 0) {
    float r = acc + b2v;
    if (row < N) onsite[row] = r; else coup[row - N] = r;
  }
}

// ---------- dna mask + per-graph local index (single wave) ----------
__global__ void k_dna(const float* __restrict__ x, const int* __restrict__ batch,
                      int* __restrict__ dna, int* __restrict__ loc, int N, int B) {
  __shared__ int perB[64];
  __shared__ int beforeB[64];
  int l = threadIdx.x;
  perB[l] = 0;
  __syncthreads();
  int chunk = (N + 63) >> 6;
  int s0 = l * chunk, s1 = min(N, s0 + chunk);
  int cnt = 0;
  for (int n = s0; n < s1; ++n) {
    int mi = (x[n * 4 + 0] != 0.f || x[n * 4 + 1] != 0.f ||
              x[n * 4 + 2] != 0.f || x[n * 4 + 3] != 0.f) ? 1 : 0;
    dna[n] = mi;
    cnt += mi;
    if (mi) atomicAdd(&perB[batch[n]], 1);
  }
  __syncthreads();
  int pre = cnt;
#pragma unroll
  for (int off = 1; off < 64; off <<= 1) {
    int o = __shfl_up(pre, off);
    if (l >= off) pre += o;
  }
  int excl = pre - cnt;
  if (l == 0) {
    int run = 0;
    for (int g = 0; g < B; ++g) { beforeB[g] = run; run += perB[g]; }
  }
  __syncthreads();
  int run = excl;
  for (int n = s0; n < s1; ++n) {
    loc[n] = run - beforeB[batch[n]];
    run += dna[n];
  }
}

// ---------- H init (0 off-diag, 1e-6 diag) ----------
__global__ void k_hinit(float* __restrict__ H, int total) {
  int idx = blockIdx.x * 256 + threadIdx.x;
  if (idx >= total) return;
  int ij = idx & (HSZ * HSZ - 1);
  H[idx] = ((ij >> 7) == (ij & 127)) ? 1e-6f : 0.f;
}

// ---------- H scatter-add: onsite diag + symmetric coupling ----------
__global__ void k_hadd(const int* __restrict__ dna, const int* __restrict__ loc,
                       const int* __restrict__ batch, const int* __restrict__ srcI,
                       const int* __restrict__ dstI, const float* __restrict__ onsite,
                       const float* __restrict__ coup, float* __restrict__ H, int N, int E) {
  int item = blockIdx.x * 256 + threadIdx.x;
  if (item >= N + E) return;
  if (item < N) {
    if (dna[item]) atomicAdd(&H[batch[item] * (HSZ * HSZ) + loc[item] * (HSZ + 1)], onsite[item]);
  } else {
    int ei = item - N;
    int s = srcI[ei], d = dstI[ei];
    if (dna[s] && dna[d]) {
      float cv = coup[ei];
      int b = batch[s];
      atomicAdd(&H[b * (HSZ * HSZ) + loc[s] * HSZ + loc[d]], cv);
      atomicAdd(&H[b * (HSZ * HSZ) + loc[d] * HSZ + loc[s]], cv);
    }
  }
}

// ---------- NEGF: Gr = inv((E*I - H) + i*diag(g)) via complex in-place ----------
// Gauss-Jordan w/ partial pivoting. 512 threads/block, 4x8 complex tile/thread.
// R4-R7 ladder: named-scalar tile (no local arrays); stay at VGPR<=64 arch regs
// (accumulator tile spills into AGPR half of unified file -> ~4 waves/EU).
// R8 (this round): instruction diet. The k-loop is unrolled 8x (16 outer x 8
// compile-time inner) so par=k&1 and the staged-column element index
// mck=(k+1)&7 become constants: the CSEL4 cndmask chains (~80 VALU/iter issued
// by EVERY wave since tc== hits 4 lanes of each) fold to direct register refs,
// and the pivot-row e0..e7 fixup compares collapse to a single tc==kb element
// write. Pivoted-row mask for pmag staging moves from rowk[] LDS reads to a
// per-thread register bitmask ('used', updated from the broadcast p). Pivot
// reciprocal: v_rcp + 1 Newton step instead of the IEEE divide chain.
// prow stride 10 (80 B, 16B-aligned) -> q loads are 4x ds_read_b128.
#define CSEL4(V, I) ((I) == 0 ? (V).x : (I) == 1 ? (V).y : (I) == 2 ? (V).z : (V).w)
#define GET8(VA, VB, I) ((I) < 4 ? CSEL4(VA, (I)) : CSEL4(VB, (I) - 4))
#define SETC4(V, I, X) do { if ((I) == 0) (V).x = (X); else if ((I) == 1) (V).y = (X); \
                            else if ((I) == 2) (V).z = (X); else (V).w = (X); } while (0)
#define SET8(VA, VB, I, X) do { if ((I) < 4) SETC4(VA, (I), X); else SETC4(VB, (I) - 4, X); } while (0)

__device__ __forceinline__ unsigned packm(float re, float im, int row) {
  float m = re * re + im * im;
  return (__float_as_uint(m) & 0xFFFFFF80u) | (unsigned)row;
}

__global__ __attribute__((amdgpu_flat_work_group_size(512, 512), amdgpu_waves_per_eu(4, 4)))
void k_negf(
    const float* __restrict__ Hm, const float* __restrict__ GL, const float* __restrict__ GR,
    float* __restrict__ outT, float* __restrict__ outD) {
  int bid = blockIdx.x;
  int b = bid / NEGRID, eix = bid % NEGRID;
  float Ev = (float)(-3.0 + (6.0 / 99.0) * (double)eix);

  int tid = threadIdx.x;
  int tr = tid >> 4, tc = tid & 15;   // 32 row-groups x 16 col-groups
  int r0 = tr << 2, c0 = tc << 3;     // 4 rows x 8 cols per thread

  __shared__ float gl_s[HSZ], gr_s[HSZ], g_s[HSZ];
  __shared__ float2 fcol[2][HSZ];
  __shared__ unsigned pmag[2][HSZ];
  __shared__ float2 prow[160];        // stride 10*tc: 16B-aligned, 2-way-max conflicts
  __shared__ int colrow[HSZ];         // colrow[k] = p
  __shared__ int rowk[HSZ];           // rowk[p] = k  (epilogue only)
  __shared__ float redbuf[16];

  if (tid < HSZ) {
    float a_ = GL[b * HSZ + tid], b_ = GR[b * HSZ + tid];
    gl_s[tid] = a_; gr_s[tid] = b_;
    g_s[tid] = 0.5f * (a_ + b_) + 1e-12f;
  }
  __syncthreads();

  // W tile: rows r0..r0+3, cols c0..c0+7. A = cols c0..c0+3, B = c0+4..c0+7.
  float4 rA0, rB0, iA0, iB0, rA1, rB1, iA1, iB1;
  float4 rA2, rB2, iA2, iB2, rA3, rB3, iA3, iB3;
  const float* Hb = Hm + (size_t)b * HSZ * HSZ;
#define INIT8(RA, RB, IA, IB, MR) do { \
    int r_ = r0 + MR; \
    const float4 hA = *(const float4*)(Hb + r_ * HSZ + c0); \
    const float4 hB = *(const float4*)(Hb + r_ * HSZ + c0 + 4); \
    float gv = g_s[r_]; \
    RA.x = ((c0 + 0 == r_) ? Ev : 0.f) - hA.x;  RA.y = ((c0 + 1 == r_) ? Ev : 0.f) - hA.y; \
    RA.z = ((c0 + 2 == r_) ? Ev : 0.f) - hA.z;  RA.w = ((c0 + 3 == r_) ? Ev : 0.f) - hA.w; \
    RB.x = ((c0 + 4 == r_) ? Ev : 0.f) - hB.x;  RB.y = ((c0 + 5 == r_) ? Ev : 0.f) - hB.y; \
    RB.z = ((c0 + 6 == r_) ? Ev : 0.f) - hB.z;  RB.w = ((c0 + 7 == r_) ? Ev : 0.f) - hB.w; \
    IA.x = (c0 + 0 == r_) ? gv : 0.f;  IA.y = (c0 + 1 == r_) ? gv : 0.f; \
    IA.z = (c0 + 2 == r_) ? gv : 0.f;  IA.w = (c0 + 3 == r_) ? gv : 0.f; \
    IB.x = (c0 + 4 == r_) ? gv : 0.f;  IB.y = (c0 + 5 == r_) ? gv : 0.f; \
    IB.z = (c0 + 6 == r_) ? gv : 0.f;  IB.w = (c0 + 7 == r_) ? gv : 0.f; \
  } while (0)
  INIT8(rA0, rB0, iA0, iB0, 0);
  INIT8(rA1, rB1, iA1, iB1, 1);
  INIT8(rA2, rB2, iA2, iB2, 2);
  INIT8(rA3, rB3, iA3, iB3, 3);

  if (tc == 0) {  // stage column 0
    fcol[0][r0 + 0] = make_float2(rA0.x, iA0.x); pmag[0][r0 + 0] = packm(rA0.x, iA0.x, r0 + 0);
    fcol[0][r0 + 1] = make_float2(rA1.x, iA1.x); pmag[0][r0 + 1] = packm(rA1.x, iA1.x, r0 + 1);
    fcol[0][r0 + 2] = make_float2(rA2.x, iA2.x); pmag[0][r0 + 2] = packm(rA2.x, iA2.x, r0 + 2);
    fcol[0][r0 + 3] = make_float2(rA3.x, iA3.x); pmag[0][r0 + 3] = packm(rA3.x, iA3.x, r0 + 3);
  }
  __syncthreads();

  int lane = tid & 63;
  unsigned used = 0u;                 // bit MR set once row r0+MR has been a pivot
  for (int kb = 0; kb < 16; ++kb) {
#pragma unroll
    for (int u = 0; u < 8; ++u) {
      const int k = (kb << 3) + u;
      const int par = u & 1;          // compile-time
      // --- packed per-wave argmax over 128 magnitudes (single umax chain) ---
      unsigned v1 = pmag[par][lane], v2 = pmag[par][lane + 64];
      unsigned vm = v1 > v2 ? v1 : v2;
#pragma unroll
      for (int off = 32; off; off >>= 1) {
        unsigned ov = __shfl_xor(vm, off);
        vm = ov > vm ? ov : vm;
      }
      int p = (int)(vm & 127u);
      float2 piv = fcol[par][p];
      float dmag = piv.x * piv.x + piv.y * piv.y;
      float idn = __builtin_amdgcn_rcpf(dmag);
      idn = idn * (2.0f - dmag * idn);           // 1 Newton step, ~1 ulp
      float dre = piv.x * idn, dim = -piv.y * idn;

      bool mygrp = (tr == (p >> 2));
      if (mygrp) used |= 1u << (p & 3);

      // --- pivot-row owners (one row-group): stage (w/ piv+1 at col k) + scale ---
      if (mygrp) {
        int mrp = p & 3;
        float4 sA = mrp == 0 ? rA0 : mrp == 1 ? rA1 : mrp == 2 ? rA2 : rA3;
        float4 sB = mrp == 0 ? rB0 : mrp == 1 ? rB1 : mrp == 2 ? rB2 : rB3;
        float4 tA = mrp == 0 ? iA0 : mrp == 1 ? iA1 : mrp == 2 ? iA2 : iA3;
        float4 tB = mrp == 0 ? iB0 : mrp == 1 ? iB1 : mrp == 2 ? iB2 : iB3;
        float4* pw = (float4*)&prow[10 * tc];
        pw[0] = make_float4(sA.x, tA.x, sA.y, tA.y);
        pw[1] = make_float4(sA.z, tA.z, sA.w, tA.w);
        pw[2] = make_float4(sB.x, tB.x, sB.y, tB.y);
        pw[3] = make_float4(sB.z, tB.z, sB.w, tB.w);
        if (tc == kb) prow[10 * tc + u] = make_float2(piv.x + 1.f, piv.y);
        float4 nA, nB, mA, mB;
        nA.x = sA.x * dre - tA.x * dim; mA.x = sA.x * dim + tA.x * dre;
        nA.y = sA.y * dre - tA.y * dim; mA.y = sA.y * dim + tA.y * dre;
        nA.z = sA.z * dre - tA.z * dim; mA.z = sA.z * dim + tA.z * dre;
        nA.w = sA.w * dre - tA.w * dim; mA.w = sA.w * dim + tA.w * dre;
        nB.x = sB.x * dre - tB.x * dim; mB.x = sB.x * dim + tB.x * dre;
        nB.y = sB.y * dre - tB.y * dim; mB.y = sB.y * dim + tB.y * dre;
        nB.z = sB.z * dre - tB.z * dim; mB.z = sB.z * dim + tB.z * dre;
        nB.w = sB.w * dre - tB.w * dim; mB.w = sB.w * dim + tB.w * dre;
        if (tc == kb) {                 // column k of this row -> (dre, dim)
          SET8(nA, nB, u, dre);
          SET8(mA, mB, u, dim);
        }
        if (mrp == 0)      { rA0 = nA; iA0 = mA; rB0 = nB; iB0 = mB; }
        else if (mrp == 1) { rA1 = nA; iA1 = mA; rB1 = nB; iB1 = mB; }
        else if (mrp == 2) { rA2 = nA; iA2 = mA; rB2 = nB; iB2 = mB; }
        else               { rA3 = nA; iA3 = mA; rB3 = nB; iB3 = mB; }
        if (tc == 0) { colrow[k] = p; rowk[p] = k; }
      }
      __syncthreads();

      // --- eliminate all rows != p: generic update, NO column-k special case ---
      const float4* qp = (const float4*)&prow[10 * tc];
      float4 qa = qp[0], qb = qp[1], qc = qp[2], qd = qp[3];  // (q0,q1)(q2,q3)(q4,q5)(q6,q7)
      const float4* fcp = (const float4*)&fcol[par][r0];
      float4 fa = fcp[0], fb = fcp[1];  // rows r0..r0+1, r0+2..r0+3
#define CELIM(RE, IM, QX, QY) do { \
      RE = RE - (fr * QX - fi * QY); \
      IM = IM - (fr * QY + fi * QX); \
    } while (0)
#define ELIM8(RA, IA, RB, IB, FX, FY, MR) do { \
      if (r0 + MR != p) { \
        float fr = FX * dre - FY * dim; \
        float fi = FX * dim + FY * dre; \
        CELIM(RA.x, IA.x, qa.x, qa.y); \
        CELIM(RA.y, IA.y, qa.z, qa.w); \
        CELIM(RA.z, IA.z, qb.x, qb.y); \
        CELIM(RA.w, IA.w, qb.z, qb.w); \
        CELIM(RB.x, IB.x, qc.x, qc.y); \
        CELIM(RB.y, IB.y, qc.z, qc.w); \
        CELIM(RB.z, IB.z, qd.x, qd.y); \
        CELIM(RB.w, IB.w, qd.z, qd.w); \
      } \
    } while (0)
      ELIM8(rA0, iA0, rB0, iB0, fa.x, fa.y, 0);
      ELIM8(rA1, iA1, rB1, iB1, fa.z, fa.w, 1);
      ELIM8(rA2, iA2, rB2, iB2, fb.x, fb.y, 2);
      ELIM8(rA3, iA3, rB3, iB3, fb.z, fb.w, 3);

      // --- stage column k+1 into other parity buffer (mck compile-time) ---
      if (k < HSZ - 1) {
        const int par2 = par ^ 1;
        const int mck = (u + 1) & 7;          // compile-time
        int sgrp = kb + ((u + 1) >> 3);       // kb, or kb+1 when u==7
        if (tc == sgrp) {
          float re_, im_;
#define STG8(RA, IA, RB, IB, MR) do { \
          re_ = GET8(RA, RB, mck); \
          im_ = GET8(IA, IB, mck); \
          fcol[par2][r0 + MR] = make_float2(re_, im_); \
          pmag[par2][r0 + MR] = ((used >> MR) & 1u) ? 0u : packm(re_, im_, r0 + MR); \
        } while (0)
          STG8(rA0, iA0, rB0, iB0, 0);
          STG8(rA1, iA1, rB1, iB1, 1);
          STG8(rA2, iA2, rB2, iB2, 2);
          STG8(rA3, iA3, rB3, iB3, 3);
        }
      }
      __syncthreads();
    }
  }

  // stored W[i][j] = Gr[ rowk[i] ][ colrow[j] ]  (permutation absorbed here)
  int cc0 = colrow[c0 + 0], cc1 = colrow[c0 + 1], cc2 = colrow[c0 + 2], cc3 = colrow[c0 + 3];
  int cc4 = colrow[c0 + 4], cc5 = colrow[c0 + 5], cc6 = colrow[c0 + 6], cc7 = colrow[c0 + 7];
  float gw0 = gr_s[cc0], gw1 = gr_s[cc1], gw2 = gr_s[cc2], gw3 = gr_s[cc3];
  float gw4 = gr_s[cc4], gw5 = gr_s[cc5], gw6 = gr_s[cc6], gw7 = gr_s[cc7];
  float Tacc = 0.f, Dacc = 0.f;
#define ACC8(RA, IA, RB, IB, MR) do { \
    int rr_ = rowk[r0 + MR]; \
    float glv = gl_s[rr_]; \
    float g2; \
    g2 = RA.x * RA.x + IA.x * IA.x; Tacc += glv * gw0 * g2; if (rr_ == cc0) Dacc += IA.x; \
    g2 = RA.y * RA.y + IA.y * IA.y; Tacc += glv * gw1 * g2; if (rr_ == cc1) Dacc += IA.y; \
    g2 = RA.z * RA.z + IA.z * IA.z; Tacc += glv * gw2 * g2; if (rr_ == cc2) Dacc += IA.z; \
    g2 = RA.w * RA.w + IA.w * IA.w; Tacc += glv * gw3 * g2; if (rr_ == cc3) Dacc += IA.w; \
    g2 = RB.x * RB.x + IB.x * IB.x; Tacc += glv * gw4 * g2; if (rr_ == cc4) Dacc += IB.x; \
    g2 = RB.y * RB.y + IB.y * IB.y; Tacc += glv * gw5 * g2; if (rr_ == cc5) Dacc += IB.y; \
    g2 = RB.z * RB.z + IB.z * IB.z; Tacc += glv * gw6 * g2; if (rr_ == cc6) Dacc += IB.z; \
    g2 = RB.w * RB.w + IB.w * IB.w; Tacc += glv * gw7 * g2; if (rr_ == cc7) Dacc += IB.w; \
  } while (0)
  ACC8(rA0, iA0, rB0, iB0, 0);
  ACC8(rA1, iA1, rB1, iB1, 1);
  ACC8(rA2, iA2, rB2, iB2, 2);
  ACC8(rA3, iA3, rB3, iB3, 3);
#pragma unroll
  for (int off = 32; off; off >>= 1) {
    Tacc += __shfl_xor(Tacc, off);
    Dacc += __shfl_xor(Dacc, off);
  }
  int wv = tid >> 6;
  if (lane == 0) { redbuf[wv] = Tacc; redbuf[8 + wv] = Dacc; }
  __syncthreads();
  if (tid == 0) {
    float T = 0.f, D = 0.f;
    for (int w = 0; w < 8; ++w) { T += redbuf[w]; D += redbuf[8 + w]; }
    outT[bid] = log10f(fmaxf(T, 1e-16f));
    outD[bid] = log10f(fmaxf(-D * 0.31830988618379067f, 1e-16f));
  }
}

extern "C" void kernel_launch(void* const* d_in, const int* in_sizes, int n_in,
                              void* d_out, int out_size, void* d_ws, size_t ws_size,
                              hipStream_t stream) {
  const float* x     = (const float*)d_in[0];
  const int*   eidx  = (const int*)d_in[1];
  const float* eattr = (const float*)d_in[2];
  const int*   batch = (const int*)d_in[3];
  const float* GL    = (const float*)d_in[4];
  const float* GR    = (const float*)d_in[5];
  const float* node_w  = (const float*)d_in[6];
  const float* node_b  = (const float*)d_in[7];
  const float* edgep_w = (const float*)d_in[8];
  const float* edgep_b = (const float*)d_in[9];
  const float* gat_lin      = (const float*)d_in[10];
  const float* att_src      = (const float*)d_in[11];
  const float* att_dst      = (const float*)d_in[12];
  const float* gat_lin_edge = (const float*)d_in[13];
  const float* att_edge     = (const float*)d_in[14];
  const float* gat_bias     = (const float*)d_in[15];
  const float* ln_s = (const float*)d_in[16];
  const float* ln_b = (const float*)d_in[17];
  const float* on_w1 = (const float*)d_in[18];
  const float* on_b1 = (const float*)d_in[19];
  const float* on_w2 = (const float*)d_in[20];
  const float* on_b2 = (const float*)d_in[21];
  const float* cp_w1 = (const float*)d_in[22];
  const float* cp_b1 = (const float*)d_in[23];
  const float* cp_w2 = (const float*)d_in[24];
  const float* cp_b2 = (const float*)d_in[25];

  int N = in_sizes[0] / 4;
  int E = in_sizes[1] / 2;
  int B = in_sizes[4] / HSZ;
  const int* srcI = eidx;
  const int* dstI = eidx + E;

  float* ws = (float*)d_ws;
  size_t o = 0;
  float* h     = ws + o; o += (size_t)N * 128;
  float* ebuf  = ws + o; o += (size_t)E * 128;
  float* xl    = ws + o; o += (size_t)N * 128;
  float* ssrc  = ws + o; o += (size_t)N * 4;
  float* sdst  = ws + o; o += (size_t)N * 4;
  float* sedge = ws + o; o += (size_t)E * 4;
  float* smean = ws + o; o += 16;
  float* alpha = ws + o; o += (size_t)(E + N) * 4;
  unsigned* menc = (unsigned*)(ws + o); o += (size_t)N * 4;
  float* den    = ws + o; o += (size_t)N * 4;
  float* outacc = ws + o; o += (size_t)N * 128;
  float* onsite = ws + o; o += (size_t)((N + 3) & ~3);
  float* coup   = ws + o; o += (size_t)((E + 3) & ~3);
  int* dna = (int*)(ws + o); o += (size_t)((N + 3) & ~3);
  int* loc = (int*)(ws + o); o += (size_t)((N + 3) & ~3);

  float* out  = (float*)d_out;
  float* outT = out;
  float* outD = out + (size_t)B * NEGRID;
  float* outH = out + (size_t)2 * B * NEGRID;

  k_embed<<<N + E, 128, 0, stream>>>(x, eattr, node_w, node_b, edgep_w, edgep_b,
                                     h, ebuf, smean, N, E);
  for (int l = 0; l < 4; ++l) {
    k_gat_lin<<<N + E, 128, 0, stream>>>(
        h, ebuf, gat_lin + (size_t)l * 16384, gat_lin_edge + (size_t)l * 16384,
        att_src + l * 128, att_dst + l * 128, att_edge + l * 128,
        xl, ssrc, sdst, sedge, smean + l * 4, menc, den, outacc, N, E);
    int items = (E + N) * 4;
    k_alpha<<<(items + 255) / 256, 256, 0, stream>>>(
        ssrc, sdst, sedge, smean + l * 4, srcI, dstI, alpha, menc, N, E, 1.0f / (float)E);
    k_scatter<<<E + N, 128, 0, stream>>>(alpha, menc, xl, srcI, dstI, den, outacc, N, E);
    k_norm<<<N, 128, 0, stream>>>(outacc, den, gat_bias + l * 128,
                                  ln_s + l * 128, ln_b + l * 128, h, N);
  }
  k_mlp<<<N + E, 64, 0, stream>>>(h, ebuf, on_w1, on_b1, on_w2, on_b2,
                                  cp_w1, cp_b1, cp_w2, cp_b2, onsite, coup, N, E);
  k_dna<<<1, 64, 0, stream>>>(x, batch, dna, loc, N, B);
  int htot = B * HSZ * HSZ;
  k_hinit<<<(htot + 255) / 256, 256, 0, stream>>>(outH, htot);
  k_hadd<<<(N + E + 255) / 256, 256, 0, stream>>>(dna, loc, batch, srcI, dstI,
                                                  onsite, coup, outH, N, E);
  k_negf<<<B * NEGRID, 512, 0, stream>>>(outH, GL, GR, outT, outD);
}

// Round 3
// 918.704 us; speedup vs baseline: 1.3963x; 1.3963x over previous
//
#include <hip/hip_runtime.h>

#define HSZ 128
#define NEGRID 100

// ---------- float <-> order-preserving uint (for atomic float max) ----------
__device__ __forceinline__ unsigned encf(float f) {
  unsigned i = __float_as_uint(f);
  return (i & 0x80000000u) ? ~i : (i | 0x80000000u);
}
__device__ __forceinline__ float decf(unsigned u) {
  return (u & 0x80000000u) ? __uint_as_float(u & 0x7fffffffu) : __uint_as_float(~u);
}

// ---------- h = x@node_w + node_b ; e = edge_attr@edgep_w + edgep_b ----------
__global__ void k_embed(const float* __restrict__ x, const float* __restrict__ ea,
                        const float* __restrict__ nw, const float* __restrict__ nb,
                        const float* __restrict__ ew, const float* __restrict__ eb,
                        float* __restrict__ h, float* __restrict__ e,
                        float* __restrict__ smean, int N, int E) {
  int row = blockIdx.x, c = threadIdx.x;
  if (row == 0 && c < 16) smean[c] = 0.f;
  if (row < N) {
    float acc = nb[c];
#pragma unroll
    for (int k = 0; k < 4; ++k) acc += x[row * 4 + k] * nw[k * 128 + c];
    h[row * 128 + c] = acc;
  } else {
    int ei = row - N;
    float acc = eb[c];
#pragma unroll
    for (int k = 0; k < 5; ++k) acc += ea[ei * 5 + k] * ew[k * 128 + c];
    e[ei * 128 + c] = acc;
  }
}

// ---------- per layer: xl = h@W (nodes), s_src/s_dst per node; s_edge per edge ----------
__global__ void k_gat_lin(const float* __restrict__ h, const float* __restrict__ e,
                          const float* __restrict__ W, const float* __restrict__ We,
                          const float* __restrict__ asrc, const float* __restrict__ adst,
                          const float* __restrict__ aedge,
                          float* __restrict__ xl, float* __restrict__ ssrc,
                          float* __restrict__ sdst, float* __restrict__ sedge,
                          float* __restrict__ smean4, unsigned* __restrict__ menc,
                          float* __restrict__ den, float* __restrict__ outacc,
                          int N, int E) {
  __shared__ float row_lds[128];
  __shared__ float red[128];
  __shared__ float red2[128];
  int row = blockIdx.x, c = threadIdx.x;
  const float* M;
  if (row < N) { row_lds[c] = h[row * 128 + c]; M = W; }
  else         { row_lds[c] = e[(row - N) * 128 + c]; M = We; }
  __syncthreads();
  float acc = 0.f;
  for (int k = 0; k < 128; ++k) acc += row_lds[k] * M[k * 128 + c];
  if (row < N) {
    xl[row * 128 + c] = acc;
    outacc[row * 128 + c] = 0.f;
    if (c < 4) { menc[row * 4 + c] = 0u; den[row * 4 + c] = 0.f; }
    red[c]  = acc * asrc[c];
    red2[c] = acc * adst[c];
    __syncthreads();
    if (c < 8) {
      int hh = c & 3;
      const float* b = (c < 4) ? red : red2;
      float s = 0.f;
      for (int t = 0; t < 32; ++t) s += b[hh * 32 + t];
      if (c < 4) ssrc[row * 4 + hh] = s; else sdst[row * 4 + hh] = s;
    }
  } else {
    int ei = row - N;
    red[c] = acc * aedge[c];
    __syncthreads();
    if (c < 4) {
      float s = 0.f;
      for (int t = 0; t < 32; ++t) s += red[c * 32 + t];
      sedge[ei * 4 + c] = s;
      atomicAdd(&smean4[c], s);
    }
  }
}

// ---------- alpha (leaky-relu) + atomic segment max over dst ----------
__global__ void k_alpha(const float* __restrict__ ssrc, const float* __restrict__ sdst,
                        const float* __restrict__ sedge, const float* __restrict__ smean4,
                        const int* __restrict__ srcI, const int* __restrict__ dstI,
                        float* __restrict__ alpha, unsigned* __restrict__ menc,
                        int N, int E, float invE) {
  int gid = blockIdx.x * 256 + threadIdx.x;
  if (gid >= (E + N) * 4) return;
  int item = gid >> 2, hh = gid & 3;
  float a; int dnode;
  if (item < E) {
    a = ssrc[srcI[item] * 4 + hh] + sdst[dstI[item] * 4 + hh] + sedge[item * 4 + hh];
    dnode = dstI[item];
  } else {
    int n = item - E;
    a = ssrc[n * 4 + hh] + sdst[n * 4 + hh] + smean4[hh] * invE;
    dnode = n;
  }
  a = (a > 0.f) ? a : 0.2f * a;
  alpha[gid] = a;
  atomicMax(&menc[dnode * 4 + hh], encf(a));
}

// ---------- exp + atomic den / weighted-feature scatter ----------
__global__ void k_scatter(const float* __restrict__ alpha, const unsigned* __restrict__ menc,
                          const float* __restrict__ xl, const int* __restrict__ srcI,
                          const int* __restrict__ dstI, float* __restrict__ den,
                          float* __restrict__ outacc, int N, int E) {
  int item = blockIdx.x, c = threadIdx.x, hh = c >> 5;
  int sn, dn;
  if (item < E) { sn = srcI[item]; dn = dstI[item]; } else { sn = dn = item - E; }
  float m = decf(menc[dn * 4 + hh]);
  float ex = expf(alpha[item * 4 + hh] - m);
  atomicAdd(&outacc[dn * 128 + c], xl[sn * 128 + c] * ex);
  if (c < 4) {
    float ex2 = expf(alpha[item * 4 + c] - decf(menc[dn * 4 + c]));
    atomicAdd(&den[dn * 4 + c], ex2);
  }
}

// ---------- hc = out/den + bias; h = LN(relu(hc)+h) ----------
__global__ void k_norm(const float* __restrict__ outacc, const float* __restrict__ den,
                       const float* __restrict__ bias, const float* __restrict__ lns,
                       const float* __restrict__ lnb, float* __restrict__ h, int N) {
  __shared__ float buf[128];
  int n = blockIdx.x, c = threadIdx.x, hh = c >> 5;
  float v = outacc[n * 128 + c] / den[n * 4 + hh] + bias[c];
  v = fmaxf(v, 0.f) + h[n * 128 + c];
  buf[c] = v;
  __syncthreads();
  for (int s = 64; s > 0; s >>= 1) { if (c < s) buf[c] += buf[c + s]; __syncthreads(); }
  float mean = buf[0] * (1.f / 128.f);
  __syncthreads();
  float dv = v - mean;
  buf[c] = dv * dv;
  __syncthreads();
  for (int s = 64; s > 0; s >>= 1) { if (c < s) buf[c] += buf[c + s]; __syncthreads(); }
  float var = buf[0] * (1.f / 128.f);
  h[n * 128 + c] = dv * (1.0f / sqrtf(var + 1e-5f)) * lns[c] + lnb[c];
}

// ---------- onsite / coupling MLPs (128 -> 64 -> 1) ----------
__global__ void k_mlp(const float* __restrict__ h, const float* __restrict__ e,
                      const float* __restrict__ w1n, const float* __restrict__ b1n,
                      const float* __restrict__ w2n, const float* __restrict__ b2n,
                      const float* __restrict__ w1e, const float* __restrict__ b1e,
                      const float* __restrict__ w2e, const float* __restrict__ b2e,
                      float* __restrict__ onsite, float* __restrict__ coup, int N, int E) {
  int row = blockIdx.x, t = threadIdx.x;
  const float *vec, *w1, *b1, *w2; float b2v;
  if (row < N) { vec = h + (size_t)row * 128; w1 = w1n; b1 = b1n; w2 = w2n; b2v = b2n[0]; }
  else         { vec = e + (size_t)(row - N) * 128; w1 = w1e; b1 = b1e; w2 = w2e; b2v = b2e[0]; }
  float acc = b1[t];
  for (int k = 0; k < 128; ++k) acc += vec[k] * w1[k * 64 + t];
  acc = fmaxf(acc, 0.f) * w2[t];
#pragma unroll
  for (int off = 32; off; off >>= 1) acc += __shfl_down(acc, off);
  if (t == 0) {
    float r = acc + b2v;
    if (row < N) onsite[row] = r; else coup[row - N] = r;
  }
}

// ---------- dna mask + per-graph local index (single wave) ----------
__global__ void k_dna(const float* __restrict__ x, const int* __restrict__ batch,
                      int* __restrict__ dna, int* __restrict__ loc, int N, int B) {
  __shared__ int perB[64];
  __shared__ int beforeB[64];
  int l = threadIdx.x;
  perB[l] = 0;
  __syncthreads();
  int chunk = (N + 63) >> 6;
  int s0 = l * chunk, s1 = min(N, s0 + chunk);
  int cnt = 0;
  for (int n = s0; n < s1; ++n) {
    int mi = (x[n * 4 + 0] != 0.f || x[n * 4 + 1] != 0.f ||
              x[n * 4 + 2] != 0.f || x[n * 4 + 3] != 0.f) ? 1 : 0;
    dna[n] = mi;
    cnt += mi;
    if (mi) atomicAdd(&perB[batch[n]], 1);
  }
  __syncthreads();
  int pre = cnt;
#pragma unroll
  for (int off = 1; off < 64; off <<= 1) {
    int o = __shfl_up(pre, off);
    if (l >= off) pre += o;
  }
  int excl = pre - cnt;
  if (l == 0) {
    int run = 0;
    for (int g = 0; g < B; ++g) { beforeB[g] = run; run += perB[g]; }
  }
  __syncthreads();
  int run = excl;
  for (int n = s0; n < s1; ++n) {
    loc[n] = run - beforeB[batch[n]];
    run += dna[n];
  }
}

// ---------- H init (0 off-diag, 1e-6 diag) ----------
__global__ void k_hinit(float* __restrict__ H, int total) {
  int idx = blockIdx.x * 256 + threadIdx.x;
  if (idx >= total) return;
  int ij = idx & (HSZ * HSZ - 1);
  H[idx] = ((ij >> 7) == (ij & 127)) ? 1e-6f : 0.f;
}

// ---------- H scatter-add: onsite diag + symmetric coupling ----------
__global__ void k_hadd(const int* __restrict__ dna, const int* __restrict__ loc,
                       const int* __restrict__ batch, const int* __restrict__ srcI,
                       const int* __restrict__ dstI, const float* __restrict__ onsite,
                       const float* __restrict__ coup, float* __restrict__ H, int N, int E) {
  int item = blockIdx.x * 256 + threadIdx.x;
  if (item >= N + E) return;
  if (item < N) {
    if (dna[item]) atomicAdd(&H[batch[item] * (HSZ * HSZ) + loc[item] * (HSZ + 1)], onsite[item]);
  } else {
    int ei = item - N;
    int s = srcI[ei], d = dstI[ei];
    if (dna[s] && dna[d]) {
      float cv = coup[ei];
      int b = batch[s];
      atomicAdd(&H[b * (HSZ * HSZ) + loc[s] * HSZ + loc[d]], cv);
      atomicAdd(&H[b * (HSZ * HSZ) + loc[d] * HSZ + loc[s]], cv);
    }
  }
}

// ---------- NEGF: Gr = inv((E*I - H) + i*diag(g)) via complex in-place ----------
// Gauss-Jordan w/ partial pivoting. 512 threads/block, 4x8 complex tile/thread.
// R4-R7 ladder: named-scalar tile, VGPR<=64 arch + AGPR overflow, waves_per_eu(4,4).
// R8 FAILED: 8x full-body unroll -> RA spill (WRITE_SIZE 2.2->43 MB). Lesson: no
// code-bloating unrolls that stretch tile live ranges.
// R9 FAILED: LDS-recompute stager. fcol[par2] holds column k-1 (stale by 2 elim
// steps), not column k+1; current col-k+1 values live ONLY in owner registers.
// Lesson: staged column MUST be extracted from the register tile.
// R10 (this round): R7 structure with two surgical diets, both spill-safe:
//  (a) extraction CSEL chain (runtime mck, ~90 VALU paid in every wave's issue
//      stream) -> wave-uniform switch((k+1)&7): scalar branch to 8 tiny static-
//      component cases (register moves + 4 ds_write_b64), no cndmasks, no
//      live-range growth.
//  (b) phase-A argmax (2 LDS loads + 6 dependent bpermute-max, ~400cy, all
//      waves in lockstep) -> staging threads pre-reduce their 4 pmags (3 umax)
//      and combine via one LDS atomicMax into double-buffered slotu[par2],
//      overlapped with other waves' ELIM FMAs. Phase A = broadcast read of
//      slotu + fcol[p]. slotu[par] reset in phase B (barrier-separated from
//      its phase-A reads and from the next iteration's atomicMax writes).
//      pmag[2][128] LDS deleted; pivoted-row mask = register bitmask 'used'
//      (R8-validated).
//  (c) rcp + 1 Newton step pivot reciprocal (R8-validated, ~1 ulp).
// prow stride 10 (80 B, 16B-aligned) -> q loads are 4x ds_read_b128.
__device__ __forceinline__ unsigned packm(float re, float im, int row) {
  float m = re * re + im * im;
  return (__float_as_uint(m) & 0xFFFFFF80u) | (unsigned)row;
}

__global__ __attribute__((amdgpu_flat_work_group_size(512, 512), amdgpu_waves_per_eu(4, 4)))
void k_negf(
    const float* __restrict__ Hm, const float* __restrict__ GL, const float* __restrict__ GR,
    float* __restrict__ outT, float* __restrict__ outD) {
  int bid = blockIdx.x;
  int b = bid / NEGRID, eix = bid % NEGRID;
  float Ev = (float)(-3.0 + (6.0 / 99.0) * (double)eix);

  int tid = threadIdx.x;
  int tr = tid >> 4, tc = tid & 15;   // 32 row-groups x 16 col-groups
  int r0 = tr << 2, c0 = tc << 3;     // 4 rows x 8 cols per thread

  __shared__ float gl_s[HSZ], gr_s[HSZ], g_s[HSZ];
  __shared__ float2 fcol[2][HSZ];
  __shared__ float2 prow[160];        // stride 10*tc: 16B-aligned, 2-way-max conflicts
  __shared__ int colrow[HSZ];         // colrow[k] = p
  __shared__ int rowk[HSZ];           // rowk[p] = k  (epilogue only)
  __shared__ unsigned slotu[2];       // double-buffered packed argmax winner
  __shared__ float redbuf[16];

  if (tid < HSZ) {
    float a_ = GL[b * HSZ + tid], b_ = GR[b * HSZ + tid];
    gl_s[tid] = a_; gr_s[tid] = b_;
    g_s[tid] = 0.5f * (a_ + b_) + 1e-12f;
  }
  if (tid == 0) { slotu[0] = 0u; slotu[1] = 0u; }
  __syncthreads();

  // W tile: rows r0..r0+3, cols c0..c0+7. A = cols c0..c0+3, B = c0+4..c0+7.
  float4 rA0, rB0, iA0, iB0, rA1, rB1, iA1, iB1;
  float4 rA2, rB2, iA2, iB2, rA3, rB3, iA3, iB3;
  const float* Hb = Hm + (size_t)b * HSZ * HSZ;
#define INIT8(RA, RB, IA, IB, MR) do { \
    int r_ = r0 + MR; \
    const float4 hA = *(const float4*)(Hb + r_ * HSZ + c0); \
    const float4 hB = *(const float4*)(Hb + r_ * HSZ + c0 + 4); \
    float gv = g_s[r_]; \
    RA.x = ((c0 + 0 == r_) ? Ev : 0.f) - hA.x;  RA.y = ((c0 + 1 == r_) ? Ev : 0.f) - hA.y; \
    RA.z = ((c0 + 2 == r_) ? Ev : 0.f) - hA.z;  RA.w = ((c0 + 3 == r_) ? Ev : 0.f) - hA.w; \
    RB.x = ((c0 + 4 == r_) ? Ev : 0.f) - hB.x;  RB.y = ((c0 + 5 == r_) ? Ev : 0.f) - hB.y; \
    RB.z = ((c0 + 6 == r_) ? Ev : 0.f) - hB.z;  RB.w = ((c0 + 7 == r_) ? Ev : 0.f) - hB.w; \
    IA.x = (c0 + 0 == r_) ? gv : 0.f;  IA.y = (c0 + 1 == r_) ? gv : 0.f; \
    IA.z = (c0 + 2 == r_) ? gv : 0.f;  IA.w = (c0 + 3 == r_) ? gv : 0.f; \
    IB.x = (c0 + 4 == r_) ? gv : 0.f;  IB.y = (c0 + 5 == r_) ? gv : 0.f; \
    IB.z = (c0 + 6 == r_) ? gv : 0.f;  IB.w = (c0 + 7 == r_) ? gv : 0.f; \
  } while (0)
  INIT8(rA0, rB0, iA0, iB0, 0);
  INIT8(rA1, rB1, iA1, iB1, 1);
  INIT8(rA2, rB2, iA2, iB2, 2);
  INIT8(rA3, rB3, iA3, iB3, 3);

  if (tc == 0) {  // stage column 0 (bit-exact from the tile)
    fcol[0][r0 + 0] = make_float2(rA0.x, iA0.x);
    fcol[0][r0 + 1] = make_float2(rA1.x, iA1.x);
    fcol[0][r0 + 2] = make_float2(rA2.x, iA2.x);
    fcol[0][r0 + 3] = make_float2(rA3.x, iA3.x);
  }
  __syncthreads();

  if (tid < HSZ) {  // bootstrap argmax for k=0
    float2 cv = fcol[0][tid];
    unsigned pm = packm(cv.x, cv.y, tid);
#pragma unroll
    for (int off = 32; off; off >>= 1) {
      unsigned ov = __shfl_xor(pm, off);
      pm = ov > pm ? ov : pm;
    }
    if ((tid & 63) == 0) atomicMax(&slotu[0], pm);
  }
  __syncthreads();

  int lane = tid & 63;
  unsigned used = 0u;                 // bit MR set once row r0+MR has been a pivot
  for (int k = 0; k < HSZ; ++k) {
    int par = k & 1, par2 = par ^ 1;
    // --- phase A: broadcast-read precomputed pivot ---
    int p = (int)(slotu[par] & 127u);
    float2 piv = fcol[par][p];
    float dmag = piv.x * piv.x + piv.y * piv.y;
    float idn = __builtin_amdgcn_rcpf(dmag);
    idn = idn * (2.0f - dmag * idn);           // 1 Newton step, ~1 ulp
    float dre = piv.x * idn, dim = -piv.y * idn;

    if (tid == 0) { colrow[k] = p; rowk[p] = k; }

    // --- pivot-row owners (one row-group): stage (w/ piv+1 at col k) + scale ---
    if (tr == (p >> 2)) {
      used |= 1u << (p & 3);
      int mrp = p & 3;
      float4 sA = mrp == 0 ? rA0 : mrp == 1 ? rA1 : mrp == 2 ? rA2 : rA3;
      float4 sB = mrp == 0 ? rB0 : mrp == 1 ? rB1 : mrp == 2 ? rB2 : rB3;
      float4 tA = mrp == 0 ? iA0 : mrp == 1 ? iA1 : mrp == 2 ? iA2 : iA3;
      float4 tB = mrp == 0 ? iB0 : mrp == 1 ? iB1 : mrp == 2 ? iB2 : iB3;
      float4* pw = (float4*)&prow[10 * tc];
      pw[0] = make_float4(sA.x, tA.x, sA.y, tA.y);
      pw[1] = make_float4(sA.z, tA.z, sA.w, tA.w);
      pw[2] = make_float4(sB.x, tB.x, sB.y, tB.y);
      pw[3] = make_float4(sB.z, tB.z, sB.w, tB.w);
      bool e0 = (c0 + 0 == k), e1 = (c0 + 1 == k), e2 = (c0 + 2 == k), e3 = (c0 + 3 == k);
      bool e4 = (c0 + 4 == k), e5 = (c0 + 5 == k), e6 = (c0 + 6 == k), e7 = (c0 + 7 == k);
      if (tc == (k >> 3)) prow[10 * tc + (k & 7)] = make_float2(piv.x + 1.f, piv.y);
      float4 nA, nB, mA, mB;
      nA.x = sA.x * dre - tA.x * dim; mA.x = sA.x * dim + tA.x * dre;
      nA.y = sA.y * dre - tA.y * dim; mA.y = sA.y * dim + tA.y * dre;
      nA.z = sA.z * dre - tA.z * dim; mA.z = sA.z * dim + tA.z * dre;
      nA.w = sA.w * dre - tA.w * dim; mA.w = sA.w * dim + tA.w * dre;
      nB.x = sB.x * dre - tB.x * dim; mB.x = sB.x * dim + tB.x * dre;
      nB.y = sB.y * dre - tB.y * dim; mB.y = sB.y * dim + tB.y * dre;
      nB.z = sB.z * dre - tB.z * dim; mB.z = sB.z * dim + tB.z * dre;
      nB.w = sB.w * dre - tB.w * dim; mB.w = sB.w * dim + tB.w * dre;
      if (e0) { nA.x = dre; mA.x = dim; }
      if (e1) { nA.y = dre; mA.y = dim; }
      if (e2) { nA.z = dre; mA.z = dim; }
      if (e3) { nA.w = dre; mA.w = dim; }
      if (e4) { nB.x = dre; mB.x = dim; }
      if (e5) { nB.y = dre; mB.y = dim; }
      if (e6) { nB.z = dre; mB.z = dim; }
      if (e7) { nB.w = dre; mB.w = dim; }
      if (mrp == 0)      { rA0 = nA; iA0 = mA; rB0 = nB; iB0 = mB; }
      else if (mrp == 1) { rA1 = nA; iA1 = mA; rB1 = nB; iB1 = mB; }
      else if (mrp == 2) { rA2 = nA; iA2 = mA; rB2 = nB; iB2 = mB; }
      else               { rA3 = nA; iA3 = mA; rB3 = nB; iB3 = mB; }
    }
    __syncthreads();

    // --- phase B ---
    if (tid == 0) slotu[par] = 0u;   // reset consumed slot (next write is next iter, barrier-safe)

    // eliminate all rows != p: generic update, NO column-k special case
    const float4* qp = (const float4*)&prow[10 * tc];
    float4 qa = qp[0], qb = qp[1], qc = qp[2], qd = qp[3];  // (q0,q1)(q2,q3)(q4,q5)(q6,q7)
    const float4* fcp = (const float4*)&fcol[par][r0];
    float4 fa = fcp[0], fb = fcp[1];  // rows r0..r0+1, r0+2..r0+3
#define CELIM(RE, IM, QX, QY) do { \
      RE = RE - (fr * QX - fi * QY); \
      IM = IM - (fr * QY + fi * QX); \
    } while (0)
#define ELIM8(RA, IA, RB, IB, FX, FY, MR) do { \
      if (r0 + MR != p) { \
        float fr = FX * dre - FY * dim; \
        float fi = FX * dim + FY * dre; \
        CELIM(RA.x, IA.x, qa.x, qa.y); \
        CELIM(RA.y, IA.y, qa.z, qa.w); \
        CELIM(RA.z, IA.z, qb.x, qb.y); \
        CELIM(RA.w, IA.w, qb.z, qb.w); \
        CELIM(RB.x, IB.x, qc.x, qc.y); \
        CELIM(RB.y, IB.y, qc.z, qc.w); \
        CELIM(RB.z, IB.z, qd.x, qd.y); \
        CELIM(RB.w, IB.w, qd.z, qd.w); \
      } \
    } while (0)
    ELIM8(rA0, iA0, rB0, iB0, fa.x, fa.y, 0);
    ELIM8(rA1, iA1, rB1, iB1, fa.z, fa.w, 1);
    ELIM8(rA2, iA2, rB2, iB2, fb.x, fb.y, 2);
    ELIM8(rA3, iA3, rB3, iB3, fb.z, fb.w, 3);

    // --- stage column k+1 (owner col-group, wave-uniform switch) + argmax ---
    if (k < HSZ - 1) {
      int kn = k + 1;
      if (tc == (kn >> 3)) {
        float2 v0, v1, v2, v3;
#define STGA(C) do { v0 = make_float2(rA0.C, iA0.C); v1 = make_float2(rA1.C, iA1.C); \
                     v2 = make_float2(rA2.C, iA2.C); v3 = make_float2(rA3.C, iA3.C); } while (0)
#define STGB(C) do { v0 = make_float2(rB0.C, iB0.C); v1 = make_float2(rB1.C, iB1.C); \
                     v2 = make_float2(rB2.C, iB2.C); v3 = make_float2(rB3.C, iB3.C); } while (0)
        switch (kn & 7) {            // wave-uniform: scalar branch, static components
          case 0: STGA(x); break;
          case 1: STGA(y); break;
          case 2: STGA(z); break;
          case 3: STGA(w); break;
          case 4: STGB(x); break;
          case 5: STGB(y); break;
          case 6: STGB(z); break;
          default: STGB(w); break;
        }
        fcol[par2][r0 + 0] = v0;
        fcol[par2][r0 + 1] = v1;
        fcol[par2][r0 + 2] = v2;
        fcol[par2][r0 + 3] = v3;
        unsigned pm0 = (used & 1u) ? 0u : packm(v0.x, v0.y, r0 + 0);
        unsigned pm1 = (used & 2u) ? 0u : packm(v1.x, v1.y, r0 + 1);
        unsigned pm2 = (used & 4u) ? 0u : packm(v2.x, v2.y, r0 + 2);
        unsigned pm3 = (used & 8u) ? 0u : packm(v3.x, v3.y, r0 + 3);
        unsigned pm = pm0 > pm1 ? pm0 : pm1;
        unsigned pn = pm2 > pm3 ? pm2 : pm3;
        pm = pm > pn ? pm : pn;
        atomicMax(&slotu[par2], pm);
      }
    }
    __syncthreads();
  }

  // stored W[i][j] = Gr[ rowk[i] ][ colrow[j] ]  (permutation absorbed here)
  int cc0 = colrow[c0 + 0], cc1 = colrow[c0 + 1], cc2 = colrow[c0 + 2], cc3 = colrow[c0 + 3];
  int cc4 = colrow[c0 + 4], cc5 = colrow[c0 + 5], cc6 = colrow[c0 + 6], cc7 = colrow[c0 + 7];
  float gw0 = gr_s[cc0], gw1 = gr_s[cc1], gw2 = gr_s[cc2], gw3 = gr_s[cc3];
  float gw4 = gr_s[cc4], gw5 = gr_s[cc5], gw6 = gr_s[cc6], gw7 = gr_s[cc7];
  float Tacc = 0.f, Dacc = 0.f;
#define ACC8(RA, IA, RB, IB, MR) do { \
    int rr_ = rowk[r0 + MR]; \
    float glv = gl_s[rr_]; \
    float g2; \
    g2 = RA.x * RA.x + IA.x * IA.x; Tacc += glv * gw0 * g2; if (rr_ == cc0) Dacc += IA.x; \
    g2 = RA.y * RA.y + IA.y * IA.y; Tacc += glv * gw1 * g2; if (rr_ == cc1) Dacc += IA.y; \
    g2 = RA.z * RA.z + IA.z * IA.z; Tacc += glv * gw2 * g2; if (rr_ == cc2) Dacc += IA.z; \
    g2 = RA.w * RA.w + IA.w * IA.w; Tacc += glv * gw3 * g2; if (rr_ == cc3) Dacc += IA.w; \
    g2 = RB.x * RB.x + IB.x * IB.x; Tacc += glv * gw4 * g2; if (rr_ == cc4) Dacc += IB.x; \
    g2 = RB.y * RB.y + IB.y * IB.y; Tacc += glv * gw5 * g2; if (rr_ == cc5) Dacc += IB.y; \
    g2 = RB.z * RB.z + IB.z * IB.z; Tacc += glv * gw6 * g2; if (rr_ == cc6) Dacc += IB.z; \
    g2 = RB.w * RB.w + IB.w * IB.w; Tacc += glv * gw7 * g2; if (rr_ == cc7) Dacc += IB.w; \
  } while (0)
  ACC8(rA0, iA0, rB0, iB0, 0);
  ACC8(rA1, iA1, rB1, iB1, 1);
  ACC8(rA2, iA2, rB2, iB2, 2);
  ACC8(rA3, iA3, rB3, iB3, 3);
#pragma unroll
  for (int off = 32; off; off >>= 1) {
    Tacc += __shfl_xor(Tacc, off);
    Dacc += __shfl_xor(Dacc, off);
  }
  int wv = tid >> 6;
  if (lane == 0) { redbuf[wv] = Tacc; redbuf[8 + wv] = Dacc; }
  __syncthreads();
  if (tid == 0) {
    float T = 0.f, D = 0.f;
    for (int w = 0; w < 8; ++w) { T += redbuf[w]; D += redbuf[8 + w]; }
    outT[bid] = log10f(fmaxf(T, 1e-16f));
    outD[bid] = log10f(fmaxf(-D * 0.31830988618379067f, 1e-16f));
  }
}

extern "C" void kernel_launch(void* const* d_in, const int* in_sizes, int n_in,
                              void* d_out, int out_size, void* d_ws, size_t ws_size,
                              hipStream_t stream) {
  const float* x     = (const float*)d_in[0];
  const int*   eidx  = (const int*)d_in[1];
  const float* eattr = (const float*)d_in[2];
  const int*   batch = (const int*)d_in[3];
  const float* GL    = (const float*)d_in[4];
  const float* GR    = (const float*)d_in[5];
  const float* node_w  = (const float*)d_in[6];
  const float* node_b  = (const float*)d_in[7];
  const float* edgep_w = (const float*)d_in[8];
  const float* edgep_b = (const float*)d_in[9];
  const float* gat_lin      = (const float*)d_in[10];
  const float* att_src      = (const float*)d_in[11];
  const float* att_dst      = (const float*)d_in[12];
  const float* gat_lin_edge = (const float*)d_in[13];
  const float* att_edge     = (const float*)d_in[14];
  const float* gat_bias     = (const float*)d_in[15];
  const float* ln_s = (const float*)d_in[16];
  const float* ln_b = (const float*)d_in[17];
  const float* on_w1 = (const float*)d_in[18];
  const float* on_b1 = (const float*)d_in[19];
  const float* on_w2 = (const float*)d_in[20];
  const float* on_b2 = (const float*)d_in[21];
  const float* cp_w1 = (const float*)d_in[22];
  const float* cp_b1 = (const float*)d_in[23];
  const float* cp_w2 = (const float*)d_in[24];
  const float* cp_b2 = (const float*)d_in[25];

  int N = in_sizes[0] / 4;
  int E = in_sizes[1] / 2;
  int B = in_sizes[4] / HSZ;
  const int* srcI = eidx;
  const int* dstI = eidx + E;

  float* ws = (float*)d_ws;
  size_t o = 0;
  float* h     = ws + o; o += (size_t)N * 128;
  float* ebuf  = ws + o; o += (size_t)E * 128;
  float* xl    = ws + o; o += (size_t)N * 128;
  float* ssrc  = ws + o; o += (size_t)N * 4;
  float* sdst  = ws + o; o += (size_t)N * 4;
  float* sedge = ws + o; o += (size_t)E * 4;
  float* smean = ws + o; o += 16;
  float* alpha = ws + o; o += (size_t)(E + N) * 4;
  unsigned* menc = (unsigned*)(ws + o); o += (size_t)N * 4;
  float* den    = ws + o; o += (size_t)N * 4;
  float* outacc = ws + o; o += (size_t)N * 128;
  float* onsite = ws + o; o += (size_t)((N + 3) & ~3);
  float* coup   = ws + o; o += (size_t)((E + 3) & ~3);
  int* dna = (int*)(ws + o); o += (size_t)((N + 3) & ~3);
  int* loc = (int*)(ws + o); o += (size_t)((N + 3) & ~3);

  float* out  = (float*)d_out;
  float* outT = out;
  float* outD = out + (size_t)B * NEGRID;
  float* outH = out + (size_t)2 * B * NEGRID;

  k_embed<<<N + E, 128, 0, stream>>>(x, eattr, node_w, node_b, edgep_w, edgep_b,
                                     h, ebuf, smean, N, E);
  for (int l = 0; l < 4; ++l) {
    k_gat_lin<<<N + E, 128, 0, stream>>>(
        h, ebuf, gat_lin + (size_t)l * 16384, gat_lin_edge + (size_t)l * 16384,
        att_src + l * 128, att_dst + l * 128, att_edge + l * 128,
        xl, ssrc, sdst, sedge, smean + l * 4, menc, den, outacc, N, E);
    int items = (E + N) * 4;
    k_alpha<<<(items + 255) / 256, 256, 0, stream>>>(
        ssrc, sdst, sedge, smean + l * 4, srcI, dstI, alpha, menc, N, E, 1.0f / (float)E);
    k_scatter<<<E + N, 128, 0, stream>>>(alpha, menc, xl, srcI, dstI, den, outacc, N, E);
    k_norm<<<N, 128, 0, stream>>>(outacc, den, gat_bias + l * 128,
                                  ln_s + l * 128, ln_b + l * 128, h, N);
  }
  k_mlp<<<N + E, 64, 0, stream>>>(h, ebuf, on_w1, on_b1, on_w2, on_b2,
                                  cp_w1, cp_b1, cp_w2, cp_b2, onsite, coup, N, E);
  k_dna<<<1, 64, 0, stream>>>(x, batch, dna, loc, N, B);
  int htot = B * HSZ * HSZ;
  k_hinit<<<(htot + 255) / 256, 256, 0, stream>>>(outH, htot);
  k_hadd<<<(N + E + 255) / 256, 256, 0, stream>>>(dna, loc, batch, srcI, dstI,
                                                  onsite, coup, outH, N, E);
  k_negf<<<B * NEGRID, 512, 0, stream>>>(outH, GL, GR, outT, outD);
}

// Round 4
// 875.811 us; speedup vs baseline: 1.4647x; 1.0490x over previous
//
#include <hip/hip_runtime.h>

#define HSZ 128
#define NEGRID 100

// ---------- float <-> order-preserving uint (for atomic float max) ----------
__device__ __forceinline__ unsigned encf(float f) {
  unsigned i = __float_as_uint(f);
  return (i & 0x80000000u) ? ~i : (i | 0x80000000u);
}
__device__ __forceinline__ float decf(unsigned u) {
  return (u & 0x80000000u) ? __uint_as_float(u & 0x7fffffffu) : __uint_as_float(~u);
}

// ---------- h = x@node_w + node_b ; e = edge_attr@edgep_w + edgep_b ----------
__global__ void k_embed(const float* __restrict__ x, const float* __restrict__ ea,
                        const float* __restrict__ nw, const float* __restrict__ nb,
                        const float* __restrict__ ew, const float* __restrict__ eb,
                        float* __restrict__ h, float* __restrict__ e,
                        float* __restrict__ smean, int N, int E) {
  int row = blockIdx.x, c = threadIdx.x;
  if (row == 0 && c < 16) smean[c] = 0.f;
  if (row < N) {
    float acc = nb[c];
#pragma unroll
    for (int k = 0; k < 4; ++k) acc += x[row * 4 + k] * nw[k * 128 + c];
    h[row * 128 + c] = acc;
  } else {
    int ei = row - N;
    float acc = eb[c];
#pragma unroll
    for (int k = 0; k < 5; ++k) acc += ea[ei * 5 + k] * ew[k * 128 + c];
    e[ei * 128 + c] = acc;
  }
}

// ---------- per layer: xl = h@W (nodes), s_src/s_dst per node; s_edge per edge ----------
__global__ void k_gat_lin(const float* __restrict__ h, const float* __restrict__ e,
                          const float* __restrict__ W, const float* __restrict__ We,
                          const float* __restrict__ asrc, const float* __restrict__ adst,
                          const float* __restrict__ aedge,
                          float* __restrict__ xl, float* __restrict__ ssrc,
                          float* __restrict__ sdst, float* __restrict__ sedge,
                          float* __restrict__ smean4, unsigned* __restrict__ menc,
                          float* __restrict__ den, float* __restrict__ outacc,
                          int N, int E) {
  __shared__ float row_lds[128];
  __shared__ float red[128];
  __shared__ float red2[128];
  int row = blockIdx.x, c = threadIdx.x;
  const float* M;
  if (row < N) { row_lds[c] = h[row * 128 + c]; M = W; }
  else         { row_lds[c] = e[(row - N) * 128 + c]; M = We; }
  __syncthreads();
  float acc = 0.f;
  for (int k = 0; k < 128; ++k) acc += row_lds[k] * M[k * 128 + c];
  if (row < N) {
    xl[row * 128 + c] = acc;
    outacc[row * 128 + c] = 0.f;
    if (c < 4) { menc[row * 4 + c] = 0u; den[row * 4 + c] = 0.f; }
    red[c]  = acc * asrc[c];
    red2[c] = acc * adst[c];
    __syncthreads();
    if (c < 8) {
      int hh = c & 3;
      const float* b = (c < 4) ? red : red2;
      float s = 0.f;
      for (int t = 0; t < 32; ++t) s += b[hh * 32 + t];
      if (c < 4) ssrc[row * 4 + hh] = s; else sdst[row * 4 + hh] = s;
    }
  } else {
    int ei = row - N;
    red[c] = acc * aedge[c];
    __syncthreads();
    if (c < 4) {
      float s = 0.f;
      for (int t = 0; t < 32; ++t) s += red[c * 32 + t];
      sedge[ei * 4 + c] = s;
      atomicAdd(&smean4[c], s);
    }
  }
}

// ---------- alpha (leaky-relu) + atomic segment max over dst ----------
__global__ void k_alpha(const float* __restrict__ ssrc, const float* __restrict__ sdst,
                        const float* __restrict__ sedge, const float* __restrict__ smean4,
                        const int* __restrict__ srcI, const int* __restrict__ dstI,
                        float* __restrict__ alpha, unsigned* __restrict__ menc,
                        int N, int E, float invE) {
  int gid = blockIdx.x * 256 + threadIdx.x;
  if (gid >= (E + N) * 4) return;
  int item = gid >> 2, hh = gid & 3;
  float a; int dnode;
  if (item < E) {
    a = ssrc[srcI[item] * 4 + hh] + sdst[dstI[item] * 4 + hh] + sedge[item * 4 + hh];
    dnode = dstI[item];
  } else {
    int n = item - E;
    a = ssrc[n * 4 + hh] + sdst[n * 4 + hh] + smean4[hh] * invE;
    dnode = n;
  }
  a = (a > 0.f) ? a : 0.2f * a;
  alpha[gid] = a;
  atomicMax(&menc[dnode * 4 + hh], encf(a));
}

// ---------- exp + atomic den / weighted-feature scatter ----------
__global__ void k_scatter(const float* __restrict__ alpha, const unsigned* __restrict__ menc,
                          const float* __restrict__ xl, const int* __restrict__ srcI,
                          const int* __restrict__ dstI, float* __restrict__ den,
                          float* __restrict__ outacc, int N, int E) {
  int item = blockIdx.x, c = threadIdx.x, hh = c >> 5;
  int sn, dn;
  if (item < E) { sn = srcI[item]; dn = dstI[item]; } else { sn = dn = item - E; }
  float m = decf(menc[dn * 4 + hh]);
  float ex = expf(alpha[item * 4 + hh] - m);
  atomicAdd(&outacc[dn * 128 + c], xl[sn * 128 + c] * ex);
  if (c < 4) {
    float ex2 = expf(alpha[item * 4 + c] - decf(menc[dn * 4 + c]));
    atomicAdd(&den[dn * 4 + c], ex2);
  }
}

// ---------- hc = out/den + bias; h = LN(relu(hc)+h) ----------
__global__ void k_norm(const float* __restrict__ outacc, const float* __restrict__ den,
                       const float* __restrict__ bias, const float* __restrict__ lns,
                       const float* __restrict__ lnb, float* __restrict__ h, int N) {
  __shared__ float buf[128];
  int n = blockIdx.x, c = threadIdx.x, hh = c >> 5;
  float v = outacc[n * 128 + c] / den[n * 4 + hh] + bias[c];
  v = fmaxf(v, 0.f) + h[n * 128 + c];
  buf[c] = v;
  __syncthreads();
  for (int s = 64; s > 0; s >>= 1) { if (c < s) buf[c] += buf[c + s]; __syncthreads(); }
  float mean = buf[0] * (1.f / 128.f);
  __syncthreads();
  float dv = v - mean;
  buf[c] = dv * dv;
  __syncthreads();
  for (int s = 64; s > 0; s >>= 1) { if (c < s) buf[c] += buf[c + s]; __syncthreads(); }
  float var = buf[0] * (1.f / 128.f);
  h[n * 128 + c] = dv * (1.0f / sqrtf(var + 1e-5f)) * lns[c] + lnb[c];
}

// ---------- onsite / coupling MLPs (128 -> 64 -> 1) ----------
__global__ void k_mlp(const float* __restrict__ h, const float* __restrict__ e,
                      const float* __restrict__ w1n, const float* __restrict__ b1n,
                      const float* __restrict__ w2n, const float* __restrict__ b2n,
                      const float* __restrict__ w1e, const float* __restrict__ b1e,
                      const float* __restrict__ w2e, const float* __restrict__ b2e,
                      float* __restrict__ onsite, float* __restrict__ coup, int N, int E) {
  int row = blockIdx.x, t = threadIdx.x;
  const float *vec, *w1, *b1, *w2; float b2v;
  if (row < N) { vec = h + (size_t)row * 128; w1 = w1n; b1 = b1n; w2 = w2n; b2v = b2n[0]; }
  else         { vec = e + (size_t)(row - N) * 128; w1 = w1e; b1 = b1e; w2 = w2e; b2v = b2e[0]; }
  float acc = b1[t];
  for (int k = 0; k < 128; ++k) acc += vec[k] * w1[k * 64 + t];
  acc = fmaxf(acc, 0.f) * w2[t];
#pragma unroll
  for (int off = 32; off; off >>= 1) acc += __shfl_down(acc, off);
  if (t == 0) {
    float r = acc + b2v;
    if (row < N) onsite[row] = r; else coup[row - N] = r;
  }
}

// ---------- dna mask + per-graph local index (single wave) ----------
__global__ void k_dna(const float* __restrict__ x, const int* __restrict__ batch,
                      int* __restrict__ dna, int* __restrict__ loc, int N, int B) {
  __shared__ int perB[64];
  __shared__ int beforeB[64];
  int l = threadIdx.x;
  perB[l] = 0;
  __syncthreads();
  int chunk = (N + 63) >> 6;
  int s0 = l * chunk, s1 = min(N, s0 + chunk);
  int cnt = 0;
  for (int n = s0; n < s1; ++n) {
    int mi = (x[n * 4 + 0] != 0.f || x[n * 4 + 1] != 0.f ||
              x[n * 4 + 2] != 0.f || x[n * 4 + 3] != 0.f) ? 1 : 0;
    dna[n] = mi;
    cnt += mi;
    if (mi) atomicAdd(&perB[batch[n]], 1);
  }
  __syncthreads();
  int pre = cnt;
#pragma unroll
  for (int off = 1; off < 64; off <<= 1) {
    int o = __shfl_up(pre, off);
    if (l >= off) pre += o;
  }
  int excl = pre - cnt;
  if (l == 0) {
    int run = 0;
    for (int g = 0; g < B; ++g) { beforeB[g] = run; run += perB[g]; }
  }
  __syncthreads();
  int run = excl;
  for (int n = s0; n < s1; ++n) {
    loc[n] = run - beforeB[batch[n]];
    run += dna[n];
  }
}

// ---------- H init (0 off-diag, 1e-6 diag) ----------
__global__ void k_hinit(float* __restrict__ H, int total) {
  int idx = blockIdx.x * 256 + threadIdx.x;
  if (idx >= total) return;
  int ij = idx & (HSZ * HSZ - 1);
  H[idx] = ((ij >> 7) == (ij & 127)) ? 1e-6f : 0.f;
}

// ---------- H scatter-add: onsite diag + symmetric coupling ----------
__global__ void k_hadd(const int* __restrict__ dna, const int* __restrict__ loc,
                       const int* __restrict__ batch, const int* __restrict__ srcI,
                       const int* __restrict__ dstI, const float* __restrict__ onsite,
                       const float* __restrict__ coup, float* __restrict__ H, int N, int E) {
  int item = blockIdx.x * 256 + threadIdx.x;
  if (item >= N + E) return;
  if (item < N) {
    if (dna[item]) atomicAdd(&H[batch[item] * (HSZ * HSZ) + loc[item] * (HSZ + 1)], onsite[item]);
  } else {
    int ei = item - N;
    int s = srcI[ei], d = dstI[ei];
    if (dna[s] && dna[d]) {
      float cv = coup[ei];
      int b = batch[s];
      atomicAdd(&H[b * (HSZ * HSZ) + loc[s] * HSZ + loc[d]], cv);
      atomicAdd(&H[b * (HSZ * HSZ) + loc[d] * HSZ + loc[s]], cv);
    }
  }
}

// ---------- NEGF: Gr = inv((E*I - H) + i*diag(g)) via complex in-place ----------
// Gauss-Jordan w/ partial pivoting.
// R10 (662us): 512 thr x 4x8 tile, dedicated staging switch + precomputed argmax
// in slotu[2]. Counter math: 524 VALU/thread/iter measured vs ~262 counted ->
// ~2x inflation consistent with 64arch+64AGPR split (waves_per_eu(4,4) budget
// 128) streaming the AGPR-resident tile through arch VGPRs every iter.
// R11 (this round): 1024 threads x (2 rows x 8 cols) interleaved-complex tile
// (32 floats/thread). Lean body targets <=64 total regs -> waves_per_eu(8,8):
// 0 AGPRs, 8 waves/SIMD, 2 blocks/CU (100% occupancy cap). Changes:
//  - q consumed in two float4 halves (peak q regs 8 not 16)
//  - CEL via nested fmaf: 4 FMA/complex element (neg = free input modifier)
//  - pivot-row guard fr=fi=0 (cndmask) instead of divergent per-row branch
//  - pivot block specialized by mrp (no selects); stager argmax pre-reduced
//    via 2 shfl_xor among the 4 stager lanes/wave -> 1 atomicMax per wave
// Sync/slot discipline identical to R10 (validated race-free).
// prow stride 10 (80 B, 16B-aligned); same-address LDS reads broadcast free.
__device__ __forceinline__ unsigned packm(float re, float im, int row) {
  float m = re * re + im * im;
  return (__float_as_uint(m) & 0xFFFFFF80u) | (unsigned)row;
}

__global__ __attribute__((amdgpu_flat_work_group_size(1024, 1024), amdgpu_waves_per_eu(8, 8)))
void k_negf(
    const float* __restrict__ Hm, const float* __restrict__ GL, const float* __restrict__ GR,
    float* __restrict__ outT, float* __restrict__ outD) {
  int bid = blockIdx.x;
  int b = bid / NEGRID, eix = bid % NEGRID;
  float Ev = (float)(-3.0 + (6.0 / 99.0) * (double)eix);

  int tid = threadIdx.x;
  int tr = tid >> 4, tc = tid & 15;   // 64 row-groups x 16 col-groups
  int r0 = tr << 1, c0 = tc << 3;     // 2 rows x 8 cols per thread

  __shared__ float gl_s[HSZ], gr_s[HSZ], g_s[HSZ];
  __shared__ float2 fcol[2][HSZ];
  __shared__ float2 prow[160];        // stride 10*tc: 16B-aligned
  __shared__ int colrow[HSZ];         // colrow[k] = p
  __shared__ int rowk[HSZ];           // rowk[p] = k  (epilogue only)
  __shared__ unsigned slotu[2];       // double-buffered packed argmax winner
  __shared__ float redbuf[32];

  if (tid < HSZ) {
    float a_ = GL[b * HSZ + tid], b_ = GR[b * HSZ + tid];
    gl_s[tid] = a_; gr_s[tid] = b_;
    g_s[tid] = 0.5f * (a_ + b_) + 1e-12f;
  }
  if (tid == 0) { slotu[0] = 0u; slotu[1] = 0u; }
  __syncthreads();

  // Interleaved complex tile: zRC = W[r0+R][c0+C] as (re, im).
  float2 z00, z01, z02, z03, z04, z05, z06, z07;
  float2 z10, z11, z12, z13, z14, z15, z16, z17;
  const float* Hb = Hm + (size_t)b * HSZ * HSZ;
#define INITR(Z0, Z1, Z2, Z3, Z4, Z5, Z6, Z7, RR) do { \
    int r_ = r0 + RR; \
    const float4 hA = *(const float4*)(Hb + r_ * HSZ + c0); \
    const float4 hB = *(const float4*)(Hb + r_ * HSZ + c0 + 4); \
    float gv = g_s[r_]; \
    Z0 = make_float2(((c0 + 0 == r_) ? Ev : 0.f) - hA.x, (c0 + 0 == r_) ? gv : 0.f); \
    Z1 = make_float2(((c0 + 1 == r_) ? Ev : 0.f) - hA.y, (c0 + 1 == r_) ? gv : 0.f); \
    Z2 = make_float2(((c0 + 2 == r_) ? Ev : 0.f) - hA.z, (c0 + 2 == r_) ? gv : 0.f); \
    Z3 = make_float2(((c0 + 3 == r_) ? Ev : 0.f) - hA.w, (c0 + 3 == r_) ? gv : 0.f); \
    Z4 = make_float2(((c0 + 4 == r_) ? Ev : 0.f) - hB.x, (c0 + 4 == r_) ? gv : 0.f); \
    Z5 = make_float2(((c0 + 5 == r_) ? Ev : 0.f) - hB.y, (c0 + 5 == r_) ? gv : 0.f); \
    Z6 = make_float2(((c0 + 6 == r_) ? Ev : 0.f) - hB.z, (c0 + 6 == r_) ? gv : 0.f); \
    Z7 = make_float2(((c0 + 7 == r_) ? Ev : 0.f) - hB.w, (c0 + 7 == r_) ? gv : 0.f); \
  } while (0)
  INITR(z00, z01, z02, z03, z04, z05, z06, z07, 0);
  INITR(z10, z11, z12, z13, z14, z15, z16, z17, 1);

  if (tc == 0) {  // stage column 0 (bit-exact from the tile)
    fcol[0][r0] = z00;
    fcol[0][r0 + 1] = z10;
  }
  __syncthreads();

  if (tid < HSZ) {  // bootstrap argmax for k=0
    float2 cv = fcol[0][tid];
    unsigned pm = packm(cv.x, cv.y, tid);
#pragma unroll
    for (int off = 32; off; off >>= 1) {
      unsigned ov = __shfl_xor(pm, off);
      pm = ov > pm ? ov : pm;
    }
    if ((tid & 63) == 0) atomicMax(&slotu[0], pm);
  }
  __syncthreads();

  int lane = tid & 63;
  unsigned used = 0u;                 // bit R set once row r0+R has been a pivot
  for (int k = 0; k < HSZ; ++k) {
    int par = k & 1, par2 = par ^ 1;
    // --- phase A: broadcast-read precomputed pivot ---
    int p = (int)(slotu[par] & 127u);
    float2 piv = fcol[par][p];
    float dmag = piv.x * piv.x + piv.y * piv.y;
    float idn = __builtin_amdgcn_rcpf(dmag);
    idn = idn * (2.0f - dmag * idn);           // 1 Newton step, ~1 ulp
    float dre = piv.x * idn, dim = -piv.y * idn;

    if (tid == 0) { colrow[k] = p; rowk[p] = k; }

    // --- pivot-row owners (one 16-thread row-group = one wave): stage + scale ---
    if (tr == (p >> 1)) {
      int mrp = p & 1;
      used |= 1u << mrp;
      float4* pw = (float4*)&prow[10 * tc];
#define PIVSC(Z, CC) do { \
      float nx_ = Z.x * dre - Z.y * dim; \
      float ny_ = Z.x * dim + Z.y * dre; \
      Z = (c0 + CC == k) ? make_float2(dre, dim) : make_float2(nx_, ny_); \
    } while (0)
#define PIVROW(Z0, Z1, Z2, Z3, Z4, Z5, Z6, Z7) do { \
      pw[0] = make_float4(Z0.x, Z0.y, Z1.x, Z1.y); \
      pw[1] = make_float4(Z2.x, Z2.y, Z3.x, Z3.y); \
      pw[2] = make_float4(Z4.x, Z4.y, Z5.x, Z5.y); \
      pw[3] = make_float4(Z6.x, Z6.y, Z7.x, Z7.y); \
      if (tc == (k >> 3)) prow[10 * tc + (k & 7)] = make_float2(piv.x + 1.f, piv.y); \
      PIVSC(Z0, 0); PIVSC(Z1, 1); PIVSC(Z2, 2); PIVSC(Z3, 3); \
      PIVSC(Z4, 4); PIVSC(Z5, 5); PIVSC(Z6, 6); PIVSC(Z7, 7); \
    } while (0)
      if (mrp == 0) PIVROW(z00, z01, z02, z03, z04, z05, z06, z07);
      else          PIVROW(z10, z11, z12, z13, z14, z15, z16, z17);
    }
    __syncthreads();

    // --- phase B ---
    if (tid == 0) slotu[par] = 0u;   // reset consumed slot (barrier-separated)

    const float4* qp = (const float4*)&prow[10 * tc];
    const float4 fa = *(const float4*)&fcol[par][r0];  // (f0.re,f0.im,f1.re,f1.im)
    float fr0 = fa.x * dre - fa.y * dim, fi0 = fa.x * dim + fa.y * dre;
    float fr1 = fa.z * dre - fa.w * dim, fi1 = fa.z * dim + fa.w * dre;
    if (r0 == p)     { fr0 = 0.f; fi0 = 0.f; }   // pivot row: no-op update
    if (r0 + 1 == p) { fr1 = 0.f; fi1 = 0.f; }
#define CEL(Z, FR, FI, QX, QY) do { \
      Z.x = __builtin_fmaf(-(FR), QX, __builtin_fmaf( (FI), QY, Z.x)); \
      Z.y = __builtin_fmaf(-(FR), QY, __builtin_fmaf(-(FI), QX, Z.y)); \
    } while (0)
    {
      float4 qa = qp[0], qb = qp[1];   // cols 0-3 (interleaved complex)
      CEL(z00, fr0, fi0, qa.x, qa.y); CEL(z01, fr0, fi0, qa.z, qa.w);
      CEL(z02, fr0, fi0, qb.x, qb.y); CEL(z03, fr0, fi0, qb.z, qb.w);
      CEL(z10, fr1, fi1, qa.x, qa.y); CEL(z11, fr1, fi1, qa.z, qa.w);
      CEL(z12, fr1, fi1, qb.x, qb.y); CEL(z13, fr1, fi1, qb.z, qb.w);
    }
    {
      float4 qc = qp[2], qd = qp[3];   // cols 4-7
      CEL(z04, fr0, fi0, qc.x, qc.y); CEL(z05, fr0, fi0, qc.z, qc.w);
      CEL(z06, fr0, fi0, qd.x, qd.y); CEL(z07, fr0, fi0, qd.z, qd.w);
      CEL(z14, fr1, fi1, qc.x, qc.y); CEL(z15, fr1, fi1, qc.z, qc.w);
      CEL(z16, fr1, fi1, qd.x, qd.y); CEL(z17, fr1, fi1, qd.z, qd.w);
    }

    // --- stage column k+1 (owner col-group, wave-uniform switch) + argmax ---
    if (k < HSZ - 1) {
      int kn = k + 1;
      if (tc == (kn >> 3)) {
        float2 v0, v1;
        switch (kn & 7) {            // wave-uniform: scalar branch, static picks
          case 0:  v0 = z00; v1 = z10; break;
          case 1:  v0 = z01; v1 = z11; break;
          case 2:  v0 = z02; v1 = z12; break;
          case 3:  v0 = z03; v1 = z13; break;
          case 4:  v0 = z04; v1 = z14; break;
          case 5:  v0 = z05; v1 = z15; break;
          case 6:  v0 = z06; v1 = z16; break;
          default: v0 = z07; v1 = z17; break;
        }
        fcol[par2][r0] = v0;
        fcol[par2][r0 + 1] = v1;
        unsigned pm0 = (used & 1u) ? 0u : packm(v0.x, v0.y, r0);
        unsigned pm1 = (used & 2u) ? 0u : packm(v1.x, v1.y, r0 + 1);
        unsigned pm = pm0 > pm1 ? pm0 : pm1;
        // reduce across the 4 stager lanes of this wave (lanes tc, tc+16, +32, +48)
        unsigned ov = __shfl_xor(pm, 16); pm = ov > pm ? ov : pm;
        ov = __shfl_xor(pm, 32); pm = ov > pm ? ov : pm;
        if (lane < 16) atomicMax(&slotu[par2], pm);   // 1 lane per wave
      }
    }
    __syncthreads();
  }

  // stored W[i][j] = Gr[ rowk[i] ][ colrow[j] ]  (permutation absorbed here)
  int cc0 = colrow[c0 + 0], cc1 = colrow[c0 + 1], cc2 = colrow[c0 + 2], cc3 = colrow[c0 + 3];
  int cc4 = colrow[c0 + 4], cc5 = colrow[c0 + 5], cc6 = colrow[c0 + 6], cc7 = colrow[c0 + 7];
  float gw0 = gr_s[cc0], gw1 = gr_s[cc1], gw2 = gr_s[cc2], gw3 = gr_s[cc3];
  float gw4 = gr_s[cc4], gw5 = gr_s[cc5], gw6 = gr_s[cc6], gw7 = gr_s[cc7];
  float Tacc = 0.f, Dacc = 0.f;
#define ACCR(Z0, Z1, Z2, Z3, Z4, Z5, Z6, Z7, RR) do { \
    int rr_ = rowk[r0 + RR]; \
    float glv = gl_s[rr_]; \
    float g2; \
    g2 = Z0.x * Z0.x + Z0.y * Z0.y; Tacc += glv * gw0 * g2; if (rr_ == cc0) Dacc += Z0.y; \
    g2 = Z1.x * Z1.x + Z1.y * Z1.y; Tacc += glv * gw1 * g2; if (rr_ == cc1) Dacc += Z1.y; \
    g2 = Z2.x * Z2.x + Z2.y * Z2.y; Tacc += glv * gw2 * g2; if (rr_ == cc2) Dacc += Z2.y; \
    g2 = Z3.x * Z3.x + Z3.y * Z3.y; Tacc += glv * gw3 * g2; if (rr_ == cc3) Dacc += Z3.y; \
    g2 = Z4.x * Z4.x + Z4.y * Z4.y; Tacc += glv * gw4 * g2; if (rr_ == cc4) Dacc += Z4.y; \
    g2 = Z5.x * Z5.x + Z5.y * Z5.y; Tacc += glv * gw5 * g2; if (rr_ == cc5) Dacc += Z5.y; \
    g2 = Z6.x * Z6.x + Z6.y * Z6.y; Tacc += glv * gw6 * g2; if (rr_ == cc6) Dacc += Z6.y; \
    g2 = Z7.x * Z7.x + Z7.y * Z7.y; Tacc += glv * gw7 * g2; if (rr_ == cc7) Dacc += Z7.y; \
  } while (0)
  ACCR(z00, z01, z02, z03, z04, z05, z06, z07, 0);
  ACCR(z10, z11, z12, z13, z14, z15, z16, z17, 1);
#pragma unroll
  for (int off = 32; off; off >>= 1) {
    Tacc += __shfl_xor(Tacc, off);
    Dacc += __shfl_xor(Dacc, off);
  }
  int wv = tid >> 6;
  if (lane == 0) { redbuf[wv] = Tacc; redbuf[16 + wv] = Dacc; }
  __syncthreads();
  if (tid == 0) {
    float T = 0.f, D = 0.f;
    for (int w = 0; w < 16; ++w) { T += redbuf[w]; D += redbuf[16 + w]; }
    outT[bid] = log10f(fmaxf(T, 1e-16f));
    outD[bid] = log10f(fmaxf(-D * 0.31830988618379067f, 1e-16f));
  }
}

extern "C" void kernel_launch(void* const* d_in, const int* in_sizes, int n_in,
                              void* d_out, int out_size, void* d_ws, size_t ws_size,
                              hipStream_t stream) {
  const float* x     = (const float*)d_in[0];
  const int*   eidx  = (const int*)d_in[1];
  const float* eattr = (const float*)d_in[2];
  const int*   batch = (const int*)d_in[3];
  const float* GL    = (const float*)d_in[4];
  const float* GR    = (const float*)d_in[5];
  const float* node_w  = (const float*)d_in[6];
  const float* node_b  = (const float*)d_in[7];
  const float* edgep_w = (const float*)d_in[8];
  const float* edgep_b = (const float*)d_in[9];
  const float* gat_lin      = (const float*)d_in[10];
  const float* att_src      = (const float*)d_in[11];
  const float* att_dst      = (const float*)d_in[12];
  const float* gat_lin_edge = (const float*)d_in[13];
  const float* att_edge     = (const float*)d_in[14];
  const float* gat_bias     = (const float*)d_in[15];
  const float* ln_s = (const float*)d_in[16];
  const float* ln_b = (const float*)d_in[17];
  const float* on_w1 = (const float*)d_in[18];
  const float* on_b1 = (const float*)d_in[19];
  const float* on_w2 = (const float*)d_in[20];
  const float* on_b2 = (const float*)d_in[21];
  const float* cp_w1 = (const float*)d_in[22];
  const float* cp_b1 = (const float*)d_in[23];
  const float* cp_w2 = (const float*)d_in[24];
  const float* cp_b2 = (const float*)d_in[25];

  int N = in_sizes[0] / 4;
  int E = in_sizes[1] / 2;
  int B = in_sizes[4] / HSZ;
  const int* srcI = eidx;
  const int* dstI = eidx + E;

  float* ws = (float*)d_ws;
  size_t o = 0;
  float* h     = ws + o; o += (size_t)N * 128;
  float* ebuf  = ws + o; o += (size_t)E * 128;
  float* xl    = ws + o; o += (size_t)N * 128;
  float* ssrc  = ws + o; o += (size_t)N * 4;
  float* sdst  = ws + o; o += (size_t)N * 4;
  float* sedge = ws + o; o += (size_t)E * 4;
  float* smean = ws + o; o += 16;
  float* alpha = ws + o; o += (size_t)(E + N) * 4;
  unsigned* menc = (unsigned*)(ws + o); o += (size_t)N * 4;
  float* den    = ws + o; o += (size_t)N * 4;
  float* outacc = ws + o; o += (size_t)N * 128;
  float* onsite = ws + o; o += (size_t)((N + 3) & ~3);
  float* coup   = ws + o; o += (size_t)((E + 3) & ~3);
  int* dna = (int*)(ws + o); o += (size_t)((N + 3) & ~3);
  int* loc = (int*)(ws + o); o += (size_t)((N + 3) & ~3);

  float* out  = (float*)d_out;
  float* outT = out;
  float* outD = out + (size_t)B * NEGRID;
  float* outH = out + (size_t)2 * B * NEGRID;

  k_embed<<<N + E, 128, 0, stream>>>(x, eattr, node_w, node_b, edgep_w, edgep_b,
                                     h, ebuf, smean, N, E);
  for (int l = 0; l < 4; ++l) {
    k_gat_lin<<<N + E, 128, 0, stream>>>(
        h, ebuf, gat_lin + (size_t)l * 16384, gat_lin_edge + (size_t)l * 16384,
        att_src + l * 128, att_dst + l * 128, att_edge + l * 128,
        xl, ssrc, sdst, sedge, smean + l * 4, menc, den, outacc, N, E);
    int items = (E + N) * 4;
    k_alpha<<<(items + 255) / 256, 256, 0, stream>>>(
        ssrc, sdst, sedge, smean + l * 4, srcI, dstI, alpha, menc, N, E, 1.0f / (float)E);
    k_scatter<<<E + N, 128, 0, stream>>>(alpha, menc, xl, srcI, dstI, den, outacc, N, E);
    k_norm<<<N, 128, 0, stream>>>(outacc, den, gat_bias + l * 128,
                                  ln_s + l * 128, ln_b + l * 128, h, N);
  }
  k_mlp<<<N + E, 64, 0, stream>>>(h, ebuf, on_w1, on_b1, on_w2, on_b2,
                                  cp_w1, cp_b1, cp_w2, cp_b2, onsite, coup, N, E);
  k_dna<<<1, 64, 0, stream>>>(x, batch, dna, loc, N, B);
  int htot = B * HSZ * HSZ;
  k_hinit<<<(htot + 255) / 256, 256, 0, stream>>>(outH, htot);
  k_hadd<<<(N + E + 255) / 256, 256, 0, stream>>>(dna, loc, batch, srcI, dstI,
                                                  onsite, coup, outH, N, E);
  k_negf<<<B * NEGRID, 1024, 0, stream>>>(outH, GL, GR, outT, outD);
}

// Round 5
// 657.636 us; speedup vs baseline: 1.9506x; 1.3318x over previous
//
#include <hip/hip_runtime.h>

#define HSZ 128
#define NEGRID 100

// ---------- float <-> order-preserving uint (for atomic float max) ----------
__device__ __forceinline__ unsigned encf(float f) {
  unsigned i = __float_as_uint(f);
  return (i & 0x80000000u) ? ~i : (i | 0x80000000u);
}
__device__ __forceinline__ float decf(unsigned u) {
  return (u & 0x80000000u) ? __uint_as_float(u & 0x7fffffffu) : __uint_as_float(~u);
}

// ---------- h = x@node_w + node_b ; e = edge_attr@edgep_w + edgep_b ----------
__global__ void k_embed(const float* __restrict__ x, const float* __restrict__ ea,
                        const float* __restrict__ nw, const float* __restrict__ nb,
                        const float* __restrict__ ew, const float* __restrict__ eb,
                        float* __restrict__ h, float* __restrict__ e,
                        float* __restrict__ smean, int N, int E) {
  int row = blockIdx.x, c = threadIdx.x;
  if (row == 0 && c < 16) smean[c] = 0.f;
  if (row < N) {
    float acc = nb[c];
#pragma unroll
    for (int k = 0; k < 4; ++k) acc += x[row * 4 + k] * nw[k * 128 + c];
    h[row * 128 + c] = acc;
  } else {
    int ei = row - N;
    float acc = eb[c];
#pragma unroll
    for (int k = 0; k < 5; ++k) acc += ea[ei * 5 + k] * ew[k * 128 + c];
    e[ei * 128 + c] = acc;
  }
}

// ---------- per layer: xl = h@W (nodes), s_src/s_dst per node; s_edge per edge ----------
__global__ void k_gat_lin(const float* __restrict__ h, const float* __restrict__ e,
                          const float* __restrict__ W, const float* __restrict__ We,
                          const float* __restrict__ asrc, const float* __restrict__ adst,
                          const float* __restrict__ aedge,
                          float* __restrict__ xl, float* __restrict__ ssrc,
                          float* __restrict__ sdst, float* __restrict__ sedge,
                          float* __restrict__ smean4, unsigned* __restrict__ menc,
                          float* __restrict__ den, float* __restrict__ outacc,
                          int N, int E) {
  __shared__ float row_lds[128];
  __shared__ float red[128];
  __shared__ float red2[128];
  int row = blockIdx.x, c = threadIdx.x;
  const float* M;
  if (row < N) { row_lds[c] = h[row * 128 + c]; M = W; }
  else         { row_lds[c] = e[(row - N) * 128 + c]; M = We; }
  __syncthreads();
  float acc = 0.f;
  for (int k = 0; k < 128; ++k) acc += row_lds[k] * M[k * 128 + c];
  if (row < N) {
    xl[row * 128 + c] = acc;
    outacc[row * 128 + c] = 0.f;
    if (c < 4) { menc[row * 4 + c] = 0u; den[row * 4 + c] = 0.f; }
    red[c]  = acc * asrc[c];
    red2[c] = acc * adst[c];
    __syncthreads();
    if (c < 8) {
      int hh = c & 3;
      const float* b = (c < 4) ? red : red2;
      float s = 0.f;
      for (int t = 0; t < 32; ++t) s += b[hh * 32 + t];
      if (c < 4) ssrc[row * 4 + hh] = s; else sdst[row * 4 + hh] = s;
    }
  } else {
    int ei = row - N;
    red[c] = acc * aedge[c];
    __syncthreads();
    if (c < 4) {
      float s = 0.f;
      for (int t = 0; t < 32; ++t) s += red[c * 32 + t];
      sedge[ei * 4 + c] = s;
      atomicAdd(&smean4[c], s);
    }
  }
}

// ---------- alpha (leaky-relu) + atomic segment max over dst ----------
__global__ void k_alpha(const float* __restrict__ ssrc, const float* __restrict__ sdst,
                        const float* __restrict__ sedge, const float* __restrict__ smean4,
                        const int* __restrict__ srcI, const int* __restrict__ dstI,
                        float* __restrict__ alpha, unsigned* __restrict__ menc,
                        int N, int E, float invE) {
  int gid = blockIdx.x * 256 + threadIdx.x;
  if (gid >= (E + N) * 4) return;
  int item = gid >> 2, hh = gid & 3;
  float a; int dnode;
  if (item < E) {
    a = ssrc[srcI[item] * 4 + hh] + sdst[dstI[item] * 4 + hh] + sedge[item * 4 + hh];
    dnode = dstI[item];
  } else {
    int n = item - E;
    a = ssrc[n * 4 + hh] + sdst[n * 4 + hh] + smean4[hh] * invE;
    dnode = n;
  }
  a = (a > 0.f) ? a : 0.2f * a;
  alpha[gid] = a;
  atomicMax(&menc[dnode * 4 + hh], encf(a));
}

// ---------- exp + atomic den / weighted-feature scatter ----------
__global__ void k_scatter(const float* __restrict__ alpha, const unsigned* __restrict__ menc,
                          const float* __restrict__ xl, const int* __restrict__ srcI,
                          const int* __restrict__ dstI, float* __restrict__ den,
                          float* __restrict__ outacc, int N, int E) {
  int item = blockIdx.x, c = threadIdx.x, hh = c >> 5;
  int sn, dn;
  if (item < E) { sn = srcI[item]; dn = dstI[item]; } else { sn = dn = item - E; }
  float m = decf(menc[dn * 4 + hh]);
  float ex = expf(alpha[item * 4 + hh] - m);
  atomicAdd(&outacc[dn * 128 + c], xl[sn * 128 + c] * ex);
  if (c < 4) {
    float ex2 = expf(alpha[item * 4 + c] - decf(menc[dn * 4 + c]));
    atomicAdd(&den[dn * 4 + c], ex2);
  }
}

// ---------- hc = out/den + bias; h = LN(relu(hc)+h) ----------
__global__ void k_norm(const float* __restrict__ outacc, const float* __restrict__ den,
                       const float* __restrict__ bias, const float* __restrict__ lns,
                       const float* __restrict__ lnb, float* __restrict__ h, int N) {
  __shared__ float buf[128];
  int n = blockIdx.x, c = threadIdx.x, hh = c >> 5;
  float v = outacc[n * 128 + c] / den[n * 4 + hh] + bias[c];
  v = fmaxf(v, 0.f) + h[n * 128 + c];
  buf[c] = v;
  __syncthreads();
  for (int s = 64; s > 0; s >>= 1) { if (c < s) buf[c] += buf[c + s]; __syncthreads(); }
  float mean = buf[0] * (1.f / 128.f);
  __syncthreads();
  float dv = v - mean;
  buf[c] = dv * dv;
  __syncthreads();
  for (int s = 64; s > 0; s >>= 1) { if (c < s) buf[c] += buf[c + s]; __syncthreads(); }
  float var = buf[0] * (1.f / 128.f);
  h[n * 128 + c] = dv * (1.0f / sqrtf(var + 1e-5f)) * lns[c] + lnb[c];
}

// ---------- onsite / coupling MLPs (128 -> 64 -> 1) ----------
__global__ void k_mlp(const float* __restrict__ h, const float* __restrict__ e,
                      const float* __restrict__ w1n, const float* __restrict__ b1n,
                      const float* __restrict__ w2n, const float* __restrict__ b2n,
                      const float* __restrict__ w1e, const float* __restrict__ b1e,
                      const float* __restrict__ w2e, const float* __restrict__ b2e,
                      float* __restrict__ onsite, float* __restrict__ coup, int N, int E) {
  int row = blockIdx.x, t = threadIdx.x;
  const float *vec, *w1, *b1, *w2; float b2v;
  if (row < N) { vec = h + (size_t)row * 128; w1 = w1n; b1 = b1n; w2 = w2n; b2v = b2n[0]; }
  else         { vec = e + (size_t)(row - N) * 128; w1 = w1e; b1 = b1e; w2 = w2e; b2v = b2e[0]; }
  float acc = b1[t];
  for (int k = 0; k < 128; ++k) acc += vec[k] * w1[k * 64 + t];
  acc = fmaxf(acc, 0.f) * w2[t];
#pragma unroll
  for (int off = 32; off; off >>= 1) acc += __shfl_down(acc, off);
  if (t == 0) {
    float r = acc + b2v;
    if (row < N) onsite[row] = r; else coup[row - N] = r;
  }
}

// ---------- dna mask + per-graph local index (single wave) ----------
__global__ void k_dna(const float* __restrict__ x, const int* __restrict__ batch,
                      int* __restrict__ dna, int* __restrict__ loc, int N, int B) {
  __shared__ int perB[64];
  __shared__ int beforeB[64];
  int l = threadIdx.x;
  perB[l] = 0;
  __syncthreads();
  int chunk = (N + 63) >> 6;
  int s0 = l * chunk, s1 = min(N, s0 + chunk);
  int cnt = 0;
  for (int n = s0; n < s1; ++n) {
    int mi = (x[n * 4 + 0] != 0.f || x[n * 4 + 1] != 0.f ||
              x[n * 4 + 2] != 0.f || x[n * 4 + 3] != 0.f) ? 1 : 0;
    dna[n] = mi;
    cnt += mi;
    if (mi) atomicAdd(&perB[batch[n]], 1);
  }
  __syncthreads();
  int pre = cnt;
#pragma unroll
  for (int off = 1; off < 64; off <<= 1) {
    int o = __shfl_up(pre, off);
    if (l >= off) pre += o;
  }
  int excl = pre - cnt;
  if (l == 0) {
    int run = 0;
    for (int g = 0; g < B; ++g) { beforeB[g] = run; run += perB[g]; }
  }
  __syncthreads();
  int run = excl;
  for (int n = s0; n < s1; ++n) {
    loc[n] = run - beforeB[batch[n]];
    run += dna[n];
  }
}

// ---------- H init (0 off-diag, 1e-6 diag) ----------
__global__ void k_hinit(float* __restrict__ H, int total) {
  int idx = blockIdx.x * 256 + threadIdx.x;
  if (idx >= total) return;
  int ij = idx & (HSZ * HSZ - 1);
  H[idx] = ((ij >> 7) == (ij & 127)) ? 1e-6f : 0.f;
}

// ---------- H scatter-add: onsite diag + symmetric coupling ----------
__global__ void k_hadd(const int* __restrict__ dna, const int* __restrict__ loc,
                       const int* __restrict__ batch, const int* __restrict__ srcI,
                       const int* __restrict__ dstI, const float* __restrict__ onsite,
                       const float* __restrict__ coup, float* __restrict__ H, int N, int E) {
  int item = blockIdx.x * 256 + threadIdx.x;
  if (item >= N + E) return;
  if (item < N) {
    if (dna[item]) atomicAdd(&H[batch[item] * (HSZ * HSZ) + loc[item] * (HSZ + 1)], onsite[item]);
  } else {
    int ei = item - N;
    int s = srcI[ei], d = dstI[ei];
    if (dna[s] && dna[d]) {
      float cv = coup[ei];
      int b = batch[s];
      atomicAdd(&H[b * (HSZ * HSZ) + loc[s] * HSZ + loc[d]], cv);
      atomicAdd(&H[b * (HSZ * HSZ) + loc[d] * HSZ + loc[s]], cv);
    }
  }
}

// ---------- NEGF: Gr = inv((E*I - H) + i*diag(g)) via complex in-place ----------
// R12: Gauss-Jordan WITHOUT pivoting. A = (E I - H) + i diag(g) is complex
// symmetric with PD imaginary part (Siegel upper half-space); this class is
// closed under Schur complementation, so every natural-order pivot has Im>0 --
// no-pivot GJ cannot hit a zero pivot, and pivot magnitudes stay at the
// physical broadening scale. This deletes argmax/slotu/colrow/rowk/used and
// the permutation epilogue, and enables:
//   - ownership remap: wave w owns cols [8w,8w+8), lane l owns rows 2l,2l+1.
//     Pivot-row segment q for wave w lives in ONE lane of w -> per-wave private
//     prow slot (no cross-wave handoff, no double buffer; read-early/write-late
//     in the same wave is safe: DS ops are in-order per wave and the write
//     depends on the CELs which depend on the read).
//   - ONE barrier per iteration (only the fcol column hand-off crosses waves).
//   - zero special-casing in the eliminator: store q_k = piv+1 (R10 trick) AND
//     subtract 1 from Re(f) on the pivot row. Generic z -= (f*d)*q then gives:
//     non-pivot rows -f*d at col k (inverse column), pivot row scaled by d,
//     pivot element exactly d:  piv - (piv-1)*d*(piv+1) = piv - d(piv^2-1) = d.
// 1024 thr, 2x8 complex tile (32 floats), waves_per_eu(8,8): target all-arch
// 64 VGPR (peak demand ~56; R11's spill came from the switch+argmax temps).
__global__ __attribute__((amdgpu_flat_work_group_size(1024, 1024), amdgpu_waves_per_eu(8, 8)))
void k_negf(
    const float* __restrict__ Hm, const float* __restrict__ GL, const float* __restrict__ GR,
    float* __restrict__ outT, float* __restrict__ outD) {
  int bid = blockIdx.x;
  int b = bid / NEGRID, eix = bid % NEGRID;
  float Ev = (float)(-3.0 + (6.0 / 99.0) * (double)eix);

  int tid = threadIdx.x;
  int w = tid >> 6, l = tid & 63;     // wave w: cols 8w..8w+7; lane l: rows 2l,2l+1
  int c0 = w << 3, r0 = l << 1;

  __shared__ float gl_s[HSZ], gr_s[HSZ], g_s[HSZ];
  __shared__ float2 fcol[2][HSZ];     // double-buffered current column (by row)
  __shared__ float2 prow[16 * 8];     // per-wave pivot-row segment (8 complex)
  __shared__ float redbuf[32];

  if (tid < HSZ) {
    float a_ = GL[b * HSZ + tid], b_ = GR[b * HSZ + tid];
    gl_s[tid] = a_; gr_s[tid] = b_;
    g_s[tid] = 0.5f * (a_ + b_) + 1e-12f;
  }
  __syncthreads();

  // Interleaved complex tile: zRC = W[r0+R][c0+C] as (re, im).
  float2 z00, z01, z02, z03, z04, z05, z06, z07;
  float2 z10, z11, z12, z13, z14, z15, z16, z17;
  const float* Hb = Hm + (size_t)b * HSZ * HSZ;
#define INITR(Z0, Z1, Z2, Z3, Z4, Z5, Z6, Z7, RR) do { \
    int r_ = r0 + RR; \
    const float4 hA = *(const float4*)(Hb + r_ * HSZ + c0); \
    const float4 hB = *(const float4*)(Hb + r_ * HSZ + c0 + 4); \
    float gv = g_s[r_]; \
    Z0 = make_float2(((c0 + 0 == r_) ? Ev : 0.f) - hA.x, (c0 + 0 == r_) ? gv : 0.f); \
    Z1 = make_float2(((c0 + 1 == r_) ? Ev : 0.f) - hA.y, (c0 + 1 == r_) ? gv : 0.f); \
    Z2 = make_float2(((c0 + 2 == r_) ? Ev : 0.f) - hA.z, (c0 + 2 == r_) ? gv : 0.f); \
    Z3 = make_float2(((c0 + 3 == r_) ? Ev : 0.f) - hA.w, (c0 + 3 == r_) ? gv : 0.f); \
    Z4 = make_float2(((c0 + 4 == r_) ? Ev : 0.f) - hB.x, (c0 + 4 == r_) ? gv : 0.f); \
    Z5 = make_float2(((c0 + 5 == r_) ? Ev : 0.f) - hB.y, (c0 + 5 == r_) ? gv : 0.f); \
    Z6 = make_float2(((c0 + 6 == r_) ? Ev : 0.f) - hB.z, (c0 + 6 == r_) ? gv : 0.f); \
    Z7 = make_float2(((c0 + 7 == r_) ? Ev : 0.f) - hB.w, (c0 + 7 == r_) ? gv : 0.f); \
  } while (0)
  INITR(z00, z01, z02, z03, z04, z05, z06, z07, 0);
  INITR(z10, z11, z12, z13, z14, z15, z16, z17, 1);

  // Bootstrap k=0: wave 0 stages column 0; lane 0 of each wave stages row 0
  // (its q segment), with +1 on Re at the global col-0 element (wave 0 only).
  if (w == 0) *(float4*)&fcol[0][r0] = make_float4(z00.x, z00.y, z10.x, z10.y);
  if (l == 0) {
    float2* pw = &prow[w << 3];
    pw[0] = z00; pw[1] = z01; pw[2] = z02; pw[3] = z03;
    pw[4] = z04; pw[5] = z05; pw[6] = z06; pw[7] = z07;
    if (w == 0) pw[0] = make_float2(z00.x + 1.f, z00.y);
  }
  __syncthreads();

  for (int k = 0; k < HSZ; ++k) {
    int par = k & 1, par2 = par ^ 1;
    // pivot value (broadcast) and reciprocal
    float2 pv = fcol[par][k];
    float dmag = pv.x * pv.x + pv.y * pv.y;
    float idn = __builtin_amdgcn_rcpf(dmag);
    idn = idn * (2.0f - dmag * idn);           // 1 Newton step, ~1 ulp
    float dre = pv.x * idn, dim = -pv.y * idn;

    // own-row f values; pivot row gets Re(f) -= 1 (folds scale into eliminator)
    float4 ff = *(const float4*)&fcol[par][r0];
    float f0x = ff.x - ((r0 == k) ? 1.f : 0.f);
    float f1x = ff.z - ((r0 + 1 == k) ? 1.f : 0.f);
    float fr0 = f0x * dre - ff.y * dim, fi0 = f0x * dim + ff.y * dre;
    float fr1 = f1x * dre - ff.w * dim, fi1 = f1x * dim + ff.w * dre;

    const float4* qp = (const float4*)&prow[w << 3];
#define CEL(Z, FR, FI, QX, QY) do { \
      Z.x = __builtin_fmaf(-(FR), QX, __builtin_fmaf( (FI), QY, Z.x)); \
      Z.y = __builtin_fmaf(-(FR), QY, __builtin_fmaf(-(FI), QX, Z.y)); \
    } while (0)
    {
      float4 qa = qp[0], qb = qp[1];   // cols 0-3 (interleaved complex)
      CEL(z00, fr0, fi0, qa.x, qa.y); CEL(z01, fr0, fi0, qa.z, qa.w);
      CEL(z02, fr0, fi0, qb.x, qb.y); CEL(z03, fr0, fi0, qb.z, qb.w);
      CEL(z10, fr1, fi1, qa.x, qa.y); CEL(z11, fr1, fi1, qa.z, qa.w);
      CEL(z12, fr1, fi1, qb.x, qb.y); CEL(z13, fr1, fi1, qb.z, qb.w);
    }
    {
      float4 qc = qp[2], qd = qp[3];   // cols 4-7
      CEL(z04, fr0, fi0, qc.x, qc.y); CEL(z05, fr0, fi0, qc.z, qc.w);
      CEL(z06, fr0, fi0, qd.x, qd.y); CEL(z07, fr0, fi0, qd.z, qd.w);
      CEL(z14, fr1, fi1, qc.x, qc.y); CEL(z15, fr1, fi1, qc.z, qc.w);
      CEL(z16, fr1, fi1, qd.x, qd.y); CEL(z17, fr1, fi1, qd.z, qd.w);
    }

    int kn = k + 1;
    if (kn < HSZ) {
      // stage column kn (owner wave; wave-uniform switch -> static picks)
      bool stgw = (w == (kn >> 3));
      float2 v0 = make_float2(0.f, 0.f), v1 = v0;
      if (stgw) {
        switch (kn & 7) {
          case 0:  v0 = z00; v1 = z10; break;
          case 1:  v0 = z01; v1 = z11; break;
          case 2:  v0 = z02; v1 = z12; break;
          case 3:  v0 = z03; v1 = z13; break;
          case 4:  v0 = z04; v1 = z14; break;
          case 5:  v0 = z05; v1 = z15; break;
          case 6:  v0 = z06; v1 = z16; break;
          default: v0 = z07; v1 = z17; break;
        }
        *(float4*)&fcol[par2][r0] = make_float4(v0.x, v0.y, v1.x, v1.y);
      }
      // stage q segment for step kn: lane kn>>1, row parity kn&1 (wave-uniform)
      bool myl = (l == (kn >> 1));
      float2* pw = &prow[w << 3];
      if ((kn & 1) == 0) {
        if (myl) {
          pw[0] = z00; pw[1] = z01; pw[2] = z02; pw[3] = z03;
          pw[4] = z04; pw[5] = z05; pw[6] = z06; pw[7] = z07;
        }
      } else {
        if (myl) {
          pw[0] = z10; pw[1] = z11; pw[2] = z12; pw[3] = z13;
          pw[4] = z14; pw[5] = z15; pw[6] = z16; pw[7] = z17;
        }
      }
      if (stgw && myl) {   // +1 on Re at global column kn (same lane, after raw writes)
        float2 t = (kn & 1) ? v1 : v0;
        prow[(w << 3) + (kn & 7)] = make_float2(t.x + 1.f, t.y);
      }
    }
    __syncthreads();
  }

  // W = Gr directly (no permutation). T = sum GL_i |Gr_ij|^2 GR_j; D = tr(Im Gr).
  float gw0 = gr_s[c0 + 0], gw1 = gr_s[c0 + 1], gw2 = gr_s[c0 + 2], gw3 = gr_s[c0 + 3];
  float gw4 = gr_s[c0 + 4], gw5 = gr_s[c0 + 5], gw6 = gr_s[c0 + 6], gw7 = gr_s[c0 + 7];
  float Tacc = 0.f, Dacc = 0.f;
#define ACCR(Z0, Z1, Z2, Z3, Z4, Z5, Z6, Z7, RR) do { \
    int rr_ = r0 + RR; \
    float glv = gl_s[rr_]; \
    float g2; \
    g2 = Z0.x * Z0.x + Z0.y * Z0.y; Tacc += glv * gw0 * g2; if (rr_ == c0 + 0) Dacc += Z0.y; \
    g2 = Z1.x * Z1.x + Z1.y * Z1.y; Tacc += glv * gw1 * g2; if (rr_ == c0 + 1) Dacc += Z1.y; \
    g2 = Z2.x * Z2.x + Z2.y * Z2.y; Tacc += glv * gw2 * g2; if (rr_ == c0 + 2) Dacc += Z2.y; \
    g2 = Z3.x * Z3.x + Z3.y * Z3.y; Tacc += glv * gw3 * g2; if (rr_ == c0 + 3) Dacc += Z3.y; \
    g2 = Z4.x * Z4.x + Z4.y * Z4.y; Tacc += glv * gw4 * g2; if (rr_ == c0 + 4) Dacc += Z4.y; \
    g2 = Z5.x * Z5.x + Z5.y * Z5.y; Tacc += glv * gw5 * g2; if (rr_ == c0 + 5) Dacc += Z5.y; \
    g2 = Z6.x * Z6.x + Z6.y * Z6.y; Tacc += glv * gw6 * g2; if (rr_ == c0 + 6) Dacc += Z6.y; \
    g2 = Z7.x * Z7.x + Z7.y * Z7.y; Tacc += glv * gw7 * g2; if (rr_ == c0 + 7) Dacc += Z7.y; \
  } while (0)
  ACCR(z00, z01, z02, z03, z04, z05, z06, z07, 0);
  ACCR(z10, z11, z12, z13, z14, z15, z16, z17, 1);
#pragma unroll
  for (int off = 32; off; off >>= 1) {
    Tacc += __shfl_xor(Tacc, off);
    Dacc += __shfl_xor(Dacc, off);
  }
  if (l == 0) { redbuf[w] = Tacc; redbuf[16 + w] = Dacc; }
  __syncthreads();
  if (tid == 0) {
    float T = 0.f, D = 0.f;
    for (int v = 0; v < 16; ++v) { T += redbuf[v]; D += redbuf[16 + v]; }
    outT[bid] = log10f(fmaxf(T, 1e-16f));
    outD[bid] = log10f(fmaxf(-D * 0.31830988618379067f, 1e-16f));
  }
}

extern "C" void kernel_launch(void* const* d_in, const int* in_sizes, int n_in,
                              void* d_out, int out_size, void* d_ws, size_t ws_size,
                              hipStream_t stream) {
  const float* x     = (const float*)d_in[0];
  const int*   eidx  = (const int*)d_in[1];
  const float* eattr = (const float*)d_in[2];
  const int*   batch = (const int*)d_in[3];
  const float* GL    = (const float*)d_in[4];
  const float* GR    = (const float*)d_in[5];
  const float* node_w  = (const float*)d_in[6];
  const float* node_b  = (const float*)d_in[7];
  const float* edgep_w = (const float*)d_in[8];
  const float* edgep_b = (const float*)d_in[9];
  const float* gat_lin      = (const float*)d_in[10];
  const float* att_src      = (const float*)d_in[11];
  const float* att_dst      = (const float*)d_in[12];
  const float* gat_lin_edge = (const float*)d_in[13];
  const float* att_edge     = (const float*)d_in[14];
  const float* gat_bias     = (const float*)d_in[15];
  const float* ln_s = (const float*)d_in[16];
  const float* ln_b = (const float*)d_in[17];
  const float* on_w1 = (const float*)d_in[18];
  const float* on_b1 = (const float*)d_in[19];
  const float* on_w2 = (const float*)d_in[20];
  const float* on_b2 = (const float*)d_in[21];
  const float* cp_w1 = (const float*)d_in[22];
  const float* cp_b1 = (const float*)d_in[23];
  const float* cp_w2 = (const float*)d_in[24];
  const float* cp_b2 = (const float*)d_in[25];

  int N = in_sizes[0] / 4;
  int E = in_sizes[1] / 2;
  int B = in_sizes[4] / HSZ;
  const int* srcI = eidx;
  const int* dstI = eidx + E;

  float* ws = (float*)d_ws;
  size_t o = 0;
  float* h     = ws + o; o += (size_t)N * 128;
  float* ebuf  = ws + o; o += (size_t)E * 128;
  float* xl    = ws + o; o += (size_t)N * 128;
  float* ssrc  = ws + o; o += (size_t)N * 4;
  float* sdst  = ws + o; o += (size_t)N * 4;
  float* sedge = ws + o; o += (size_t)E * 4;
  float* smean = ws + o; o += 16;
  float* alpha = ws + o; o += (size_t)(E + N) * 4;
  unsigned* menc = (unsigned*)(ws + o); o += (size_t)N * 4;
  float* den    = ws + o; o += (size_t)N * 4;
  float* outacc = ws + o; o += (size_t)N * 128;
  float* onsite = ws + o; o += (size_t)((N + 3) & ~3);
  float* coup   = ws + o; o += (size_t)((E + 3) & ~3);
  int* dna = (int*)(ws + o); o += (size_t)((N + 3) & ~3);
  int* loc = (int*)(ws + o); o += (size_t)((N + 3) & ~3);

  float* out  = (float*)d_out;
  float* outT = out;
  float* outD = out + (size_t)B * NEGRID;
  float* outH = out + (size_t)2 * B * NEGRID;

  k_embed<<<N + E, 128, 0, stream>>>(x, eattr, node_w, node_b, edgep_w, edgep_b,
                                     h, ebuf, smean, N, E);
  for (int l = 0; l < 4; ++l) {
    k_gat_lin<<<N + E, 128, 0, stream>>>(
        h, ebuf, gat_lin + (size_t)l * 16384, gat_lin_edge + (size_t)l * 16384,
        att_src + l * 128, att_dst + l * 128, att_edge + l * 128,
        xl, ssrc, sdst, sedge, smean + l * 4, menc, den, outacc, N, E);
    int items = (E + N) * 4;
    k_alpha<<<(items + 255) / 256, 256, 0, stream>>>(
        ssrc, sdst, sedge, smean + l * 4, srcI, dstI, alpha, menc, N, E, 1.0f / (float)E);
    k_scatter<<<E + N, 128, 0, stream>>>(alpha, menc, xl, srcI, dstI, den, outacc, N, E);
    k_norm<<<N, 128, 0, stream>>>(outacc, den, gat_bias + l * 128,
                                  ln_s + l * 128, ln_b + l * 128, h, N);
  }
  k_mlp<<<N + E, 64, 0, stream>>>(h, ebuf, on_w1, on_b1, on_w2, on_b2,
                                  cp_w1, cp_b1, cp_w2, cp_b2, onsite, coup, N, E);
  k_dna<<<1, 64, 0, stream>>>(x, batch, dna, loc, N, B);
  int htot = B * HSZ * HSZ;
  k_hinit<<<(htot + 255) / 256, 256, 0, stream>>>(outH, htot);
  k_hadd<<<(N + E + 255) / 256, 256, 0, stream>>>(dna, loc, batch, srcI, dstI,
                                                  onsite, coup, outH, N, E);
  k_negf<<<B * NEGRID, 1024, 0, stream>>>(outH, GL, GR, outT, outD);
}

// Round 6
// 650.317 us; speedup vs baseline: 1.9725x; 1.0113x over previous
//
#include <hip/hip_runtime.h>

#define HSZ 128
#define NEGRID 100

typedef float v2f __attribute__((ext_vector_type(2)));

// ---------- float <-> order-preserving uint (for atomic float max) ----------
__device__ __forceinline__ unsigned encf(float f) {
  unsigned i = __float_as_uint(f);
  return (i & 0x80000000u) ? ~i : (i | 0x80000000u);
}
__device__ __forceinline__ float decf(unsigned u) {
  return (u & 0x80000000u) ? __uint_as_float(u & 0x7fffffffu) : __uint_as_float(~u);
}

// ---------- h = x@node_w + node_b ; e = edge_attr@edgep_w + edgep_b ----------
__global__ void k_embed(const float* __restrict__ x, const float* __restrict__ ea,
                        const float* __restrict__ nw, const float* __restrict__ nb,
                        const float* __restrict__ ew, const float* __restrict__ eb,
                        float* __restrict__ h, float* __restrict__ e,
                        float* __restrict__ smean, int N, int E) {
  int row = blockIdx.x, c = threadIdx.x;
  if (row == 0 && c < 16) smean[c] = 0.f;
  if (row < N) {
    float acc = nb[c];
#pragma unroll
    for (int k = 0; k < 4; ++k) acc += x[row * 4 + k] * nw[k * 128 + c];
    h[row * 128 + c] = acc;
  } else {
    int ei = row - N;
    float acc = eb[c];
#pragma unroll
    for (int k = 0; k < 5; ++k) acc += ea[ei * 5 + k] * ew[k * 128 + c];
    e[ei * 128 + c] = acc;
  }
}

// ---------- per layer: xl = h@W (nodes), s_src/s_dst per node; s_edge per edge ----------
__global__ void k_gat_lin(const float* __restrict__ h, const float* __restrict__ e,
                          const float* __restrict__ W, const float* __restrict__ We,
                          const float* __restrict__ asrc, const float* __restrict__ adst,
                          const float* __restrict__ aedge,
                          float* __restrict__ xl, float* __restrict__ ssrc,
                          float* __restrict__ sdst, float* __restrict__ sedge,
                          float* __restrict__ smean4, unsigned* __restrict__ menc,
                          float* __restrict__ den, float* __restrict__ outacc,
                          int N, int E) {
  __shared__ float row_lds[128];
  __shared__ float red[128];
  __shared__ float red2[128];
  int row = blockIdx.x, c = threadIdx.x;
  const float* M;
  if (row < N) { row_lds[c] = h[row * 128 + c]; M = W; }
  else         { row_lds[c] = e[(row - N) * 128 + c]; M = We; }
  __syncthreads();
  float acc = 0.f;
  for (int k = 0; k < 128; ++k) acc += row_lds[k] * M[k * 128 + c];
  if (row < N) {
    xl[row * 128 + c] = acc;
    outacc[row * 128 + c] = 0.f;
    if (c < 4) { menc[row * 4 + c] = 0u; den[row * 4 + c] = 0.f; }
    red[c]  = acc * asrc[c];
    red2[c] = acc * adst[c];
    __syncthreads();
    if (c < 8) {
      int hh = c & 3;
      const float* b = (c < 4) ? red : red2;
      float s = 0.f;
      for (int t = 0; t < 32; ++t) s += b[hh * 32 + t];
      if (c < 4) ssrc[row * 4 + hh] = s; else sdst[row * 4 + hh] = s;
    }
  } else {
    int ei = row - N;
    red[c] = acc * aedge[c];
    __syncthreads();
    if (c < 4) {
      float s = 0.f;
      for (int t = 0; t < 32; ++t) s += red[c * 32 + t];
      sedge[ei * 4 + c] = s;
      atomicAdd(&smean4[c], s);
    }
  }
}

// ---------- alpha (leaky-relu) + atomic segment max over dst ----------
__global__ void k_alpha(const float* __restrict__ ssrc, const float* __restrict__ sdst,
                        const float* __restrict__ sedge, const float* __restrict__ smean4,
                        const int* __restrict__ srcI, const int* __restrict__ dstI,
                        float* __restrict__ alpha, unsigned* __restrict__ menc,
                        int N, int E, float invE) {
  int gid = blockIdx.x * 256 + threadIdx.x;
  if (gid >= (E + N) * 4) return;
  int item = gid >> 2, hh = gid & 3;
  float a; int dnode;
  if (item < E) {
    a = ssrc[srcI[item] * 4 + hh] + sdst[dstI[item] * 4 + hh] + sedge[item * 4 + hh];
    dnode = dstI[item];
  } else {
    int n = item - E;
    a = ssrc[n * 4 + hh] + sdst[n * 4 + hh] + smean4[hh] * invE;
    dnode = n;
  }
  a = (a > 0.f) ? a : 0.2f * a;
  alpha[gid] = a;
  atomicMax(&menc[dnode * 4 + hh], encf(a));
}

// ---------- exp + atomic den / weighted-feature scatter ----------
__global__ void k_scatter(const float* __restrict__ alpha, const unsigned* __restrict__ menc,
                          const float* __restrict__ xl, const int* __restrict__ srcI,
                          const int* __restrict__ dstI, float* __restrict__ den,
                          float* __restrict__ outacc, int N, int E) {
  int item = blockIdx.x, c = threadIdx.x, hh = c >> 5;
  int sn, dn;
  if (item < E) { sn = srcI[item]; dn = dstI[item]; } else { sn = dn = item - E; }
  float m = decf(menc[dn * 4 + hh]);
  float ex = expf(alpha[item * 4 + hh] - m);
  atomicAdd(&outacc[dn * 128 + c], xl[sn * 128 + c] * ex);
  if (c < 4) {
    float ex2 = expf(alpha[item * 4 + c] - decf(menc[dn * 4 + c]));
    atomicAdd(&den[dn * 4 + c], ex2);
  }
}

// ---------- hc = out/den + bias; h = LN(relu(hc)+h) ----------
__global__ void k_norm(const float* __restrict__ outacc, const float* __restrict__ den,
                       const float* __restrict__ bias, const float* __restrict__ lns,
                       const float* __restrict__ lnb, float* __restrict__ h, int N) {
  __shared__ float buf[128];
  int n = blockIdx.x, c = threadIdx.x, hh = c >> 5;
  float v = outacc[n * 128 + c] / den[n * 4 + hh] + bias[c];
  v = fmaxf(v, 0.f) + h[n * 128 + c];
  buf[c] = v;
  __syncthreads();
  for (int s = 64; s > 0; s >>= 1) { if (c < s) buf[c] += buf[c + s]; __syncthreads(); }
  float mean = buf[0] * (1.f / 128.f);
  __syncthreads();
  float dv = v - mean;
  buf[c] = dv * dv;
  __syncthreads();
  for (int s = 64; s > 0; s >>= 1) { if (c < s) buf[c] += buf[c + s]; __syncthreads(); }
  float var = buf[0] * (1.f / 128.f);
  h[n * 128 + c] = dv * (1.0f / sqrtf(var + 1e-5f)) * lns[c] + lnb[c];
}

// ---------- onsite / coupling MLPs (128 -> 64 -> 1) ----------
__global__ void k_mlp(const float* __restrict__ h, const float* __restrict__ e,
                      const float* __restrict__ w1n, const float* __restrict__ b1n,
                      const float* __restrict__ w2n, const float* __restrict__ b2n,
                      const float* __restrict__ w1e, const float* __restrict__ b1e,
                      const float* __restrict__ w2e, const float* __restrict__ b2e,
                      float* __restrict__ onsite, float* __restrict__ coup, int N, int E) {
  int row = blockIdx.x, t = threadIdx.x;
  const float *vec, *w1, *b1, *w2; float b2v;
  if (row < N) { vec = h + (size_t)row * 128; w1 = w1n; b1 = b1n; w2 = w2n; b2v = b2n[0]; }
  else         { vec = e + (size_t)(row - N) * 128; w1 = w1e; b1 = b1e; w2 = w2e; b2v = b2e[0]; }
  float acc = b1[t];
  for (int k = 0; k < 128; ++k) acc += vec[k] * w1[k * 64 + t];
  acc = fmaxf(acc, 0.f) * w2[t];
#pragma unroll
  for (int off = 32; off; off >>= 1) acc += __shfl_down(acc, off);
  if (t == 0) {
    float r = acc + b2v;
    if (row < N) onsite[row] = r; else coup[row - N] = r;
  }
}

// ---------- dna mask + per-graph local index (single wave) ----------
__global__ void k_dna(const float* __restrict__ x, const int* __restrict__ batch,
                      int* __restrict__ dna, int* __restrict__ loc, int N, int B) {
  __shared__ int perB[64];
  __shared__ int beforeB[64];
  int l = threadIdx.x;
  perB[l] = 0;
  __syncthreads();
  int chunk = (N + 63) >> 6;
  int s0 = l * chunk, s1 = min(N, s0 + chunk);
  int cnt = 0;
  for (int n = s0; n < s1; ++n) {
    int mi = (x[n * 4 + 0] != 0.f || x[n * 4 + 1] != 0.f ||
              x[n * 4 + 2] != 0.f || x[n * 4 + 3] != 0.f) ? 1 : 0;
    dna[n] = mi;
    cnt += mi;
    if (mi) atomicAdd(&perB[batch[n]], 1);
  }
  __syncthreads();
  int pre = cnt;
#pragma unroll
  for (int off = 1; off < 64; off <<= 1) {
    int o = __shfl_up(pre, off);
    if (l >= off) pre += o;
  }
  int excl = pre - cnt;
  if (l == 0) {
    int run = 0;
    for (int g = 0; g < B; ++g) { beforeB[g] = run; run += perB[g]; }
  }
  __syncthreads();
  int run = excl;
  for (int n = s0; n < s1; ++n) {
    loc[n] = run - beforeB[batch[n]];
    run += dna[n];
  }
}

// ---------- H init (0 off-diag, 1e-6 diag) ----------
__global__ void k_hinit(float* __restrict__ H, int total) {
  int idx = blockIdx.x * 256 + threadIdx.x;
  if (idx >= total) return;
  int ij = idx & (HSZ * HSZ - 1);
  H[idx] = ((ij >> 7) == (ij & 127)) ? 1e-6f : 0.f;
}

// ---------- H scatter-add: onsite diag + symmetric coupling ----------
__global__ void k_hadd(const int* __restrict__ dna, const int* __restrict__ loc,
                       const int* __restrict__ batch, const int* __restrict__ srcI,
                       const int* __restrict__ dstI, const float* __restrict__ onsite,
                       const float* __restrict__ coup, float* __restrict__ H, int N, int E) {
  int item = blockIdx.x * 256 + threadIdx.x;
  if (item >= N + E) return;
  if (item < N) {
    if (dna[item]) atomicAdd(&H[batch[item] * (HSZ * HSZ) + loc[item] * (HSZ + 1)], onsite[item]);
  } else {
    int ei = item - N;
    int s = srcI[ei], d = dstI[ei];
    if (dna[s] && dna[d]) {
      float cv = coup[ei];
      int b = batch[s];
      atomicAdd(&H[b * (HSZ * HSZ) + loc[s] * HSZ + loc[d]], cv);
      atomicAdd(&H[b * (HSZ * HSZ) + loc[d] * HSZ + loc[s]], cv);
    }
  }
}

// ---------- NEGF: Gr = inv((E*I - H) + i*diag(g)) via complex in-place ----------
// R12 (395us): no-pivot GJ (A in Siegel upper half-space -> natural-order
// pivots never vanish; absmax identical to pivoted), wave w owns cols 8w..8w+7,
// lane l owns rows 2l,2l+1, 1 barrier/iter, q staged in-wave, +1/-1 pivot fold.
// R13 (this round): packed FP32. Complex update z += (-fr,-fr)*(qx,qy) +
// (fi,-fi)*(qy,qx) = 2x v_pk_fma_f32 (VOP3P, with op_sel absorbing the swap)
// instead of 4 scalar FMAs. Expressed via ext_vector float2 +
// __builtin_elementwise_fma + __builtin_shufflevector so the backend can
// select pk_fma; worst case it emits the same 4 scalar FMAs (no regression).
// Pure-FMA floor for this kernel is ~85us; R12 measured ~176 VALU/thread/iter
// vs ~105 counted (32arch+32AGPR accvgpr shuffling). Packing halves the CEL
// core 64->32 instrs.
__global__ __attribute__((amdgpu_flat_work_group_size(1024, 1024), amdgpu_waves_per_eu(8, 8)))
void k_negf(
    const float* __restrict__ Hm, const float* __restrict__ GL, const float* __restrict__ GR,
    float* __restrict__ outT, float* __restrict__ outD) {
  int bid = blockIdx.x;
  int b = bid / NEGRID, eix = bid % NEGRID;
  float Ev = (float)(-3.0 + (6.0 / 99.0) * (double)eix);

  int tid = threadIdx.x;
  int w = tid >> 6, l = tid & 63;     // wave w: cols 8w..8w+7; lane l: rows 2l,2l+1
  int c0 = w << 3, r0 = l << 1;

  __shared__ float gl_s[HSZ], gr_s[HSZ], g_s[HSZ];
  __shared__ v2f fcol[2][HSZ];        // double-buffered current column (by row)
  __shared__ v2f prow[16 * 8];        // per-wave pivot-row segment (8 complex)
  __shared__ float redbuf[32];

  if (tid < HSZ) {
    float a_ = GL[b * HSZ + tid], b_ = GR[b * HSZ + tid];
    gl_s[tid] = a_; gr_s[tid] = b_;
    g_s[tid] = 0.5f * (a_ + b_) + 1e-12f;
  }
  __syncthreads();

  // Tile: zRC = W[r0+R][c0+C] as v2f (re, im).
  v2f z00, z01, z02, z03, z04, z05, z06, z07;
  v2f z10, z11, z12, z13, z14, z15, z16, z17;
  const float* Hb = Hm + (size_t)b * HSZ * HSZ;
#define INITR(Z0, Z1, Z2, Z3, Z4, Z5, Z6, Z7, RR) do { \
    int r_ = r0 + RR; \
    const float4 hA = *(const float4*)(Hb + r_ * HSZ + c0); \
    const float4 hB = *(const float4*)(Hb + r_ * HSZ + c0 + 4); \
    float gv = g_s[r_]; \
    Z0 = (v2f){((c0 + 0 == r_) ? Ev : 0.f) - hA.x, (c0 + 0 == r_) ? gv : 0.f}; \
    Z1 = (v2f){((c0 + 1 == r_) ? Ev : 0.f) - hA.y, (c0 + 1 == r_) ? gv : 0.f}; \
    Z2 = (v2f){((c0 + 2 == r_) ? Ev : 0.f) - hA.z, (c0 + 2 == r_) ? gv : 0.f}; \
    Z3 = (v2f){((c0 + 3 == r_) ? Ev : 0.f) - hA.w, (c0 + 3 == r_) ? gv : 0.f}; \
    Z4 = (v2f){((c0 + 4 == r_) ? Ev : 0.f) - hB.x, (c0 + 4 == r_) ? gv : 0.f}; \
    Z5 = (v2f){((c0 + 5 == r_) ? Ev : 0.f) - hB.y, (c0 + 5 == r_) ? gv : 0.f}; \
    Z6 = (v2f){((c0 + 6 == r_) ? Ev : 0.f) - hB.z, (c0 + 6 == r_) ? gv : 0.f}; \
    Z7 = (v2f){((c0 + 7 == r_) ? Ev : 0.f) - hB.w, (c0 + 7 == r_) ? gv : 0.f}; \
  } while (0)
  INITR(z00, z01, z02, z03, z04, z05, z06, z07, 0);
  INITR(z10, z11, z12, z13, z14, z15, z16, z17, 1);

  // Bootstrap k=0: wave 0 stages column 0; lane 0 of each wave stages row 0
  // (its q segment), with +1 on Re at the global col-0 element (wave 0 only).
  if (w == 0) { fcol[0][r0] = z00; fcol[0][r0 + 1] = z10; }
  if (l == 0) {
    v2f* pw = &prow[w << 3];
    pw[0] = z00; pw[1] = z01; pw[2] = z02; pw[3] = z03;
    pw[4] = z04; pw[5] = z05; pw[6] = z06; pw[7] = z07;
    if (w == 0) pw[0] = (v2f){z00.x + 1.f, z00.y};
  }
  __syncthreads();

  for (int k = 0; k < HSZ; ++k) {
    int par = k & 1, par2 = par ^ 1;
    // pivot value (broadcast) and reciprocal
    v2f pv = fcol[par][k];
    float dmag = pv.x * pv.x + pv.y * pv.y;
    float idn = __builtin_amdgcn_rcpf(dmag);
    idn = idn * (2.0f - dmag * idn);           // 1 Newton step, ~1 ulp
    float dre = pv.x * idn, dim = -pv.y * idn;

    // own-row f values; pivot row gets Re(f) -= 1 (folds scale into eliminator)
    v2f f0 = fcol[par][r0], f1 = fcol[par][r0 + 1];
    float f0x = f0.x - ((r0 == k) ? 1.f : 0.f);
    float f1x = f1.x - ((r0 + 1 == k) ? 1.f : 0.f);
    float fr0 = f0x * dre - f0.y * dim, fi0 = f0x * dim + f0.y * dre;
    float fr1 = f1x * dre - f1.y * dim, fi1 = f1x * dim + f1.y * dre;
    v2f ar0 = (v2f){-fr0, -fr0}, br0 = (v2f){fi0, -fi0};
    v2f ar1 = (v2f){-fr1, -fr1}, br1 = (v2f){fi1, -fi1};

    const v2f* qp = &prow[w << 3];
#define CELP(Z, AR, BR, Q, QS) do { \
      Z = __builtin_elementwise_fma(AR, Q, Z); \
      Z = __builtin_elementwise_fma(BR, QS, Z); \
    } while (0)
    {
      v2f q0 = qp[0], q1 = qp[1], q2 = qp[2], q3 = qp[3];
      v2f s0 = __builtin_shufflevector(q0, q0, 1, 0);
      v2f s1 = __builtin_shufflevector(q1, q1, 1, 0);
      v2f s2 = __builtin_shufflevector(q2, q2, 1, 0);
      v2f s3 = __builtin_shufflevector(q3, q3, 1, 0);
      CELP(z00, ar0, br0, q0, s0); CELP(z01, ar0, br0, q1, s1);
      CELP(z02, ar0, br0, q2, s2); CELP(z03, ar0, br0, q3, s3);
      CELP(z10, ar1, br1, q0, s0); CELP(z11, ar1, br1, q1, s1);
      CELP(z12, ar1, br1, q2, s2); CELP(z13, ar1, br1, q3, s3);
    }
    {
      v2f q4 = qp[4], q5 = qp[5], q6 = qp[6], q7 = qp[7];
      v2f s4 = __builtin_shufflevector(q4, q4, 1, 0);
      v2f s5 = __builtin_shufflevector(q5, q5, 1, 0);
      v2f s6 = __builtin_shufflevector(q6, q6, 1, 0);
      v2f s7 = __builtin_shufflevector(q7, q7, 1, 0);
      CELP(z04, ar0, br0, q4, s4); CELP(z05, ar0, br0, q5, s5);
      CELP(z06, ar0, br0, q6, s6); CELP(z07, ar0, br0, q7, s7);
      CELP(z14, ar1, br1, q4, s4); CELP(z15, ar1, br1, q5, s5);
      CELP(z16, ar1, br1, q6, s6); CELP(z17, ar1, br1, q7, s7);
    }

    int kn = k + 1;
    if (kn < HSZ) {
      // stage column kn (owner wave; wave-uniform switch -> static picks)
      bool stgw = (w == (kn >> 3));
      v2f v0 = (v2f){0.f, 0.f}, v1 = v0;
      if (stgw) {
        switch (kn & 7) {
          case 0:  v0 = z00; v1 = z10; break;
          case 1:  v0 = z01; v1 = z11; break;
          case 2:  v0 = z02; v1 = z12; break;
          case 3:  v0 = z03; v1 = z13; break;
          case 4:  v0 = z04; v1 = z14; break;
          case 5:  v0 = z05; v1 = z15; break;
          case 6:  v0 = z06; v1 = z16; break;
          default: v0 = z07; v1 = z17; break;
        }
        fcol[par2][r0] = v0;
        fcol[par2][r0 + 1] = v1;
      }
      // stage q segment for step kn: lane kn>>1, row parity kn&1 (wave-uniform)
      bool myl = (l == (kn >> 1));
      v2f* pw = &prow[w << 3];
      if ((kn & 1) == 0) {
        if (myl) {
          pw[0] = z00; pw[1] = z01; pw[2] = z02; pw[3] = z03;
          pw[4] = z04; pw[5] = z05; pw[6] = z06; pw[7] = z07;
        }
      } else {
        if (myl) {
          pw[0] = z10; pw[1] = z11; pw[2] = z12; pw[3] = z13;
          pw[4] = z14; pw[5] = z15; pw[6] = z16; pw[7] = z17;
        }
      }
      if (stgw && myl) {   // +1 on Re at global column kn (same lane, after raw writes)
        v2f t = (kn & 1) ? v1 : v0;
        prow[(w << 3) + (kn & 7)] = (v2f){t.x + 1.f, t.y};
      }
    }
    __syncthreads();
  }

  // W = Gr directly (no permutation). T = sum GL_i |Gr_ij|^2 GR_j; D = tr(Im Gr).
  float gw0 = gr_s[c0 + 0], gw1 = gr_s[c0 + 1], gw2 = gr_s[c0 + 2], gw3 = gr_s[c0 + 3];
  float gw4 = gr_s[c0 + 4], gw5 = gr_s[c0 + 5], gw6 = gr_s[c0 + 6], gw7 = gr_s[c0 + 7];
  float Tacc = 0.f, Dacc = 0.f;
#define ACCR(Z0, Z1, Z2, Z3, Z4, Z5, Z6, Z7, RR) do { \
    int rr_ = r0 + RR; \
    float glv = gl_s[rr_]; \
    float g2; \
    g2 = Z0.x * Z0.x + Z0.y * Z0.y; Tacc += glv * gw0 * g2; if (rr_ == c0 + 0) Dacc += Z0.y; \
    g2 = Z1.x * Z1.x + Z1.y * Z1.y; Tacc += glv * gw1 * g2; if (rr_ == c0 + 1) Dacc += Z1.y; \
    g2 = Z2.x * Z2.x + Z2.y * Z2.y; Tacc += glv * gw2 * g2; if (rr_ == c0 + 2) Dacc += Z2.y; \
    g2 = Z3.x * Z3.x + Z3.y * Z3.y; Tacc += glv * gw3 * g2; if (rr_ == c0 + 3) Dacc += Z3.y; \
    g2 = Z4.x * Z4.x + Z4.y * Z4.y; Tacc += glv * gw4 * g2; if (rr_ == c0 + 4) Dacc += Z4.y; \
    g2 = Z5.x * Z5.x + Z5.y * Z5.y; Tacc += glv * gw5 * g2; if (rr_ == c0 + 5) Dacc += Z5.y; \
    g2 = Z6.x * Z6.x + Z6.y * Z6.y; Tacc += glv * gw6 * g2; if (rr_ == c0 + 6) Dacc += Z6.y; \
    g2 = Z7.x * Z7.x + Z7.y * Z7.y; Tacc += glv * gw7 * g2; if (rr_ == c0 + 7) Dacc += Z7.y; \
  } while (0)
  ACCR(z00, z01, z02, z03, z04, z05, z06, z07, 0);
  ACCR(z10, z11, z12, z13, z14, z15, z16, z17, 1);
#pragma unroll
  for (int off = 32; off; off >>= 1) {
    Tacc += __shfl_xor(Tacc, off);
    Dacc += __shfl_xor(Dacc, off);
  }
  if (l == 0) { redbuf[w] = Tacc; redbuf[16 + w] = Dacc; }
  __syncthreads();
  if (tid == 0) {
    float T = 0.f, D = 0.f;
    for (int v = 0; v < 16; ++v) { T += redbuf[v]; D += redbuf[16 + v]; }
    outT[bid] = log10f(fmaxf(T, 1e-16f));
    outD[bid] = log10f(fmaxf(-D * 0.31830988618379067f, 1e-16f));
  }
}

extern "C" void kernel_launch(void* const* d_in, const int* in_sizes, int n_in,
                              void* d_out, int out_size, void* d_ws, size_t ws_size,
                              hipStream_t stream) {
  const float* x     = (const float*)d_in[0];
  const int*   eidx  = (const int*)d_in[1];
  const float* eattr = (const float*)d_in[2];
  const int*   batch = (const int*)d_in[3];
  const float* GL    = (const float*)d_in[4];
  const float* GR    = (const float*)d_in[5];
  const float* node_w  = (const float*)d_in[6];
  const float* node_b  = (const float*)d_in[7];
  const float* edgep_w = (const float*)d_in[8];
  const float* edgep_b = (const float*)d_in[9];
  const float* gat_lin      = (const float*)d_in[10];
  const float* att_src      = (const float*)d_in[11];
  const float* att_dst      = (const float*)d_in[12];
  const float* gat_lin_edge = (const float*)d_in[13];
  const float* att_edge     = (const float*)d_in[14];
  const float* gat_bias     = (const float*)d_in[15];
  const float* ln_s = (const float*)d_in[16];
  const float* ln_b = (const float*)d_in[17];
  const float* on_w1 = (const float*)d_in[18];
  const float* on_b1 = (const float*)d_in[19];
  const float* on_w2 = (const float*)d_in[20];
  const float* on_b2 = (const float*)d_in[21];
  const float* cp_w1 = (const float*)d_in[22];
  const float* cp_b1 = (const float*)d_in[23];
  const float* cp_w2 = (const float*)d_in[24];
  const float* cp_b2 = (const float*)d_in[25];

  int N = in_sizes[0] / 4;
  int E = in_sizes[1] / 2;
  int B = in_sizes[4] / HSZ;
  const int* srcI = eidx;
  const int* dstI = eidx + E;

  float* ws = (float*)d_ws;
  size_t o = 0;
  float* h     = ws + o; o += (size_t)N * 128;
  float* ebuf  = ws + o; o += (size_t)E * 128;
  float* xl    = ws + o; o += (size_t)N * 128;
  float* ssrc  = ws + o; o += (size_t)N * 4;
  float* sdst  = ws + o; o += (size_t)N * 4;
  float* sedge = ws + o; o += (size_t)E * 4;
  float* smean = ws + o; o += 16;
  float* alpha = ws + o; o += (size_t)(E + N) * 4;
  unsigned* menc = (unsigned*)(ws + o); o += (size_t)N * 4;
  float* den    = ws + o; o += (size_t)N * 4;
  float* outacc = ws + o; o += (size_t)N * 128;
  float* onsite = ws + o; o += (size_t)((N + 3) & ~3);
  float* coup   = ws + o; o += (size_t)((E + 3) & ~3);
  int* dna = (int*)(ws + o); o += (size_t)((N + 3) & ~3);
  int* loc = (int*)(ws + o); o += (size_t)((N + 3) & ~3);

  float* out  = (float*)d_out;
  float* outT = out;
  float* outD = out + (size_t)B * NEGRID;
  float* outH = out + (size_t)2 * B * NEGRID;

  k_embed<<<N + E, 128, 0, stream>>>(x, eattr, node_w, node_b, edgep_w, edgep_b,
                                     h, ebuf, smean, N, E);
  for (int l = 0; l < 4; ++l) {
    k_gat_lin<<<N + E, 128, 0, stream>>>(
        h, ebuf, gat_lin + (size_t)l * 16384, gat_lin_edge + (size_t)l * 16384,
        att_src + l * 128, att_dst + l * 128, att_edge + l * 128,
        xl, ssrc, sdst, sedge, smean + l * 4, menc, den, outacc, N, E);
    int items = (E + N) * 4;
    k_alpha<<<(items + 255) / 256, 256, 0, stream>>>(
        ssrc, sdst, sedge, smean + l * 4, srcI, dstI, alpha, menc, N, E, 1.0f / (float)E);
    k_scatter<<<E + N, 128, 0, stream>>>(alpha, menc, xl, srcI, dstI, den, outacc, N, E);
    k_norm<<<N, 128, 0, stream>>>(outacc, den, gat_bias + l * 128,
                                  ln_s + l * 128, ln_b + l * 128, h, N);
  }
  k_mlp<<<N + E, 64, 0, stream>>>(h, ebuf, on_w1, on_b1, on_w2, on_b2,
                                  cp_w1, cp_b1, cp_w2, cp_b2, onsite, coup, N, E);
  k_dna<<<1, 64, 0, stream>>>(x, batch, dna, loc, N, B);
  int htot = B * HSZ * HSZ;
  k_hinit<<<(htot + 255) / 256, 256, 0, stream>>>(outH, htot);
  k_hadd<<<(N + E + 255) / 256, 256, 0, stream>>>(dna, loc, batch, srcI, dstI,
                                                  onsite, coup, outH, N, E);
  k_negf<<<B * NEGRID, 1024, 0, stream>>>(outH, GL, GR, outT, outD);
}